// Round 11
// baseline (385.085 us; speedup 1.0000x reference)
//
#include <hip/hip_runtime.h>
#include <hip/hip_bf16.h>
#include <math.h>

#define N_NODES 2048
#define DIN     2048
#define HH      1024
#define LAGS    12
#define NE      65536
#define NL      (2048 * 2048)
#define CHUNK   128

#define BM 128
#define BN 128
#define BK 32

typedef __attribute__((ext_vector_type(8))) short short8;
typedef __attribute__((ext_vector_type(4))) float f32x4;

static __device__ __forceinline__ short f2bf_rne(float x) {
  union { float f; unsigned u; } c; c.f = x;
  unsigned u = c.u;
  unsigned r = (u + 0x7fffu + ((u >> 16) & 1u)) >> 16;
  return (short)r;
}
static __device__ __forceinline__ float bf2f(short h) {
  union { unsigned u; float f; } c; c.u = ((unsigned)(unsigned short)h) << 16;
  return c.f;
}

typedef __attribute__((address_space(3))) unsigned int as3_u32;
typedef const __attribute__((address_space(1))) unsigned int as1_u32c;
static __device__ __forceinline__ void gload_lds16(const void* g, void* l) {
  __builtin_amdgcn_global_load_lds((as1_u32c*)g, (as3_u32*)l, 16, 0, 0);
}

// vmcnt is PER-WAVE: each wave issues CPW global_load_lds per stage(); in
// steady state 2*CPW are outstanding; waiting for the previous tile = CPW.
#define VMCNT6  asm volatile("s_waitcnt vmcnt(6)" ::: "memory")
#define VMCNT4  asm volatile("s_waitcnt vmcnt(4)" ::: "memory")
#define VMCNT0  asm volatile("s_waitcnt vmcnt(0)" ::: "memory")
#define SBAR()  do { asm volatile("" ::: "memory"); __builtin_amdgcn_s_barrier(); \
                     asm volatile("" ::: "memory"); } while (0)

struct WCfg { const float* W; short* H; short* L; int K; int N; int nb; };
struct WCfg2 { WCfg c[2]; };
struct WCfg4 { WCfg c[4]; };

// weight transpose + hi/lo split of one 32x32 tile (L optional)
static __device__ __forceinline__ void wsplit_tile(
    const WCfg& cf, int local, int tid, float t[32][33])
{
  const float* W = cf.W;
  short* H = cf.H;
  short* L = cf.L;
  int K = cf.K, N = cf.N;
  int nbx = N >> 5;
  int bx = local % nbx, by = local / nbx;
  int tx = tid & 31, ty = tid >> 5;
  int c0 = bx << 5, k0 = by << 5;
#pragma unroll
  for (int j = 0; j < 4; ++j)
    t[ty + 8 * j][tx] = W[(size_t)(k0 + ty + 8 * j) * N + c0 + tx];
  __syncthreads();
#pragma unroll
  for (int j = 0; j < 4; ++j) {
    int c = ty + 8 * j;
    float x = t[tx][c];
    short h = f2bf_rne(x);
    size_t off = (size_t)(c0 + c) * K + k0 + tx;
    H[off] = h;
    if (L) L[off] = f2bf_rne(x - bf2f(h));
  }
}

// ---------------------------------------------------------------------------
// Mega-A: lw (2048) || encWv/decWv H-plane split (1024) || init (8).
__global__ __launch_bounds__(256) void megaA_kernel(
    const float* __restrict__ lagged, short* __restrict__ lw, WCfg2 cfgs,
    int* __restrict__ cursor, float* __restrict__ csx,
    float* __restrict__ csz, float* __restrict__ cs_gat)
{
  __shared__ float t[32][33];
  int bid = blockIdx.x;
  int tid = threadIdx.x;

  if (bid < 2048) {
    int idx = bid * 256 + tid;
    int n = idx >> 8, c8 = idx & 255;
    const float* base = lagged + (size_t)n * (LAGS * DIN) + (size_t)c8 * 8;
    float a[8] = {};
#pragma unroll
    for (int l = 0; l < LAGS; ++l) {
      float w = (float)((double)(LAGS - l) / 78.0);
      float4 v0 = *(const float4*)(base + (size_t)l * DIN);
      float4 v1 = *(const float4*)(base + (size_t)l * DIN + 4);
      a[0] += w * v0.x; a[1] += w * v0.y; a[2] += w * v0.z; a[3] += w * v0.w;
      a[4] += w * v1.x; a[5] += w * v1.y; a[6] += w * v1.z; a[7] += w * v1.w;
    }
    short8 h;
#pragma unroll
    for (int j = 0; j < 8; ++j) h[j] = f2bf_rne(a[j]);
    *(short8*)(lw + (size_t)idx * 8) = h;
  } else if (bid < 3072) {
    int wb = bid - 2048;
    int i = (wb >= cfgs.c[0].nb) ? 1 : 0;
    int local = wb - (i ? cfgs.c[0].nb : 0);
    wsplit_tile(cfgs.c[i], local, tid, t);
  } else {
    int i = (bid - 3072) * 256 + tid;   // 8 blocks -> 2048
    cursor[i] = 0; csx[i] = 0.f; csz[i] = 0.f;
    if (i < 1024) cs_gat[i] = 0.f;
  }
}

// ---------------------------------------------------------------------------
// Mega-C: encV/decV GEMM (512 blocks, single-plane B, split-K x8) ||
// fc/Wl/Wr/dec_fc weight splits (3584) || bucket-CSR fill (264).
__global__ __launch_bounds__(256) void megaC_kernel(
    const short* __restrict__ A, const short* __restrict__ Bh0,
    const short* __restrict__ Bh1, short* __restrict__ Cpart,
    WCfg4 cfgs,
    const int* __restrict__ esrc, const int* __restrict__ edst,
    int* __restrict__ cursor, int* __restrict__ csr)
{
  __shared__ char smem[32768];
  int fb = blockIdx.x;
  int tid = threadIdx.x;

  if (fb < 512) {
    // ---- gemm (2-plane): M=2048 N=256 K=2048, klen=256, ntwin=2 ----
    short* lds = (short*)smem;
    const int K = 2048, N = 256, M = 2048, klen = 256;
    int lane = tid & 63, wid = tid >> 6;
    int bn = (fb & 1) * BN;
    int bm = ((fb >> 1) & 15) * BM;
    int z = fb >> 5;
    int twin = z & 1;
    int kb = (z >> 1) * klen;
    const short* Bh = twin ? Bh1 : Bh0;

    const short* gp[4];
    int lofs[4];
    {
      int r4 = lane >> 2;
      int ksw = (lane & 3) ^ ((lane >> 3) & 3);
#pragma unroll
      for (int c = 0; c < 4; ++c) {
        int chunk = wid * 4 + c;
        int p = chunk >> 3, s = chunk & 7;
        int r = (s << 4) + r4;
        const short* bp = (p == 0) ? (A + (size_t)(bm + r) * K)
                                   : (Bh + (size_t)(bn + r) * K);
        gp[c] = bp + kb + (ksw << 3);
        lofs[c] = (p << 12) + (s << 9);
      }
    }
    auto stage = [&](int bo) {
#pragma unroll
      for (int c = 0; c < 4; ++c) {
        gload_lds16(gp[c], lds + bo + lofs[c]);
        gp[c] += BK;
      }
    };

    int l15 = lane & 15, l4 = lane >> 4;
    int wr = wid >> 1, wc = wid & 1;
    int soff = (l4 ^ ((l15 >> 1) & 3)) << 3;
    int aoff[4], bhoff[4];
#pragma unroll
    for (int i = 0; i < 4; ++i) {
      int r = wr * 64 + i * 16 + l15;
      int c = wc * 64 + i * 16 + l15;
      aoff[i]  = r * BK + soff;
      bhoff[i] = 4096 + c * BK + soff;
    }

    f32x4 acc[4][4];
#pragma unroll
    for (int m = 0; m < 4; ++m)
#pragma unroll
      for (int n = 0; n < 4; ++n) acc[m][n] = (f32x4){0.f, 0.f, 0.f, 0.f};

    stage(0);
    int cur = 0;
#pragma unroll
    for (int t = 0; t < 8; ++t) {
      if (t + 1 < 8) { stage(cur ? 0 : 8192); VMCNT4; }
      else { VMCNT0; }
      SBAR();
      const short* rb = lds + (cur ? 8192 : 0);
      short8 af[4], bh8[4];
#pragma unroll
      for (int i = 0; i < 4; ++i) {
        af[i]  = *(const short8*)(rb + aoff[i]);
        bh8[i] = *(const short8*)(rb + bhoff[i]);
      }
#pragma unroll
      for (int m = 0; m < 4; ++m)
#pragma unroll
        for (int n = 0; n < 4; ++n)
          acc[m][n] = __builtin_amdgcn_mfma_f32_16x16x32_bf16(af[m], bh8[n], acc[m][n], 0, 0, 0);
      SBAR();
      cur ^= 1;
    }

    short* P = Cpart + (size_t)z * ((size_t)M * N);
#pragma unroll
    for (int n = 0; n < 4; ++n) {
      int col = bn + wc * 64 + n * 16 + l15;
#pragma unroll
      for (int m = 0; m < 4; ++m) {
        int row0 = bm + wr * 64 + m * 16 + (l4 << 2);
#pragma unroll
        for (int r = 0; r < 4; ++r)
          P[(size_t)(row0 + r) * N + col] = f2bf_rne(acc[m][n][r]);
      }
    }
  } else if (fb < 4096) {
    // ---- weight transpose + hi/lo split (fc, Wl, Wr, dec_fc) ----
    float (*t)[33] = (float(*)[33])smem;
    int wb = fb - 512;
    int i = 0, base = 0;
    while (i < 3 && wb >= base + cfgs.c[i].nb) { base += cfgs.c[i].nb; ++i; }
    wsplit_tile(cfgs.c[i], wb - base, tid, t);
  } else {
    // ---- bucket-CSR fill: 128 slots/node; max in-degree ~52 << 128 ----
    int i = (fb - 4096) * 256 + tid;
    if (i < NE) {
      int d = edst[i];
      int p = atomicAdd(&cursor[d], 1);
      if (p < 128) csr[(d << 7) + p] = esrc[i];
    } else if (i < NE + N_NODES) {
      int nn = i - NE;
      int p = atomicAdd(&cursor[nn], 1);
      if (p < 128) csr[(nn << 7) + p] = nn;   // self-loop
    }
  }
}

// ---------------------------------------------------------------------------
// x_rec GEMM: single-plane B (hi only), split-K x2 -> bf16 partials.
// The lo-plane's contribution to csx is restored EXACTLY via the rank-1
// identity colsum(A@Bl) = colsum(A) @ Bl in xrec_sum (cs_gat from megaB).
// M=2048, N=2048, K=1024, klen=512. grid (16,16,2).
__global__ __launch_bounds__(256) void gemm_xrec(
    const short* __restrict__ A, const short* __restrict__ Bh,
    short* __restrict__ Cpart)
{
  __shared__ short lds[2 * 8192];
  const int K = 1024, N = 2048, M = 2048, klen = 512;
  int tid = threadIdx.x;
  int lane = tid & 63, wid = tid >> 6;
  int bn = blockIdx.x * BN, bm = blockIdx.y * BM;
  int z = blockIdx.z;
  int kb = z * klen;

  const short* gp[4];
  int lofs[4];
  {
    int r4 = lane >> 2;
    int ksw = (lane & 3) ^ ((lane >> 3) & 3);
#pragma unroll
    for (int c = 0; c < 4; ++c) {
      int chunk = wid * 4 + c;
      int p = chunk >> 3, s = chunk & 7;
      int r = (s << 4) + r4;
      const short* bp = (p == 0) ? (A + (size_t)(bm + r) * K)
                                 : (Bh + (size_t)(bn + r) * K);
      gp[c] = bp + kb + (ksw << 3);
      lofs[c] = (p << 12) + (s << 9);
    }
  }
  auto stage = [&](int bo) {
#pragma unroll
    for (int c = 0; c < 4; ++c) {
      gload_lds16(gp[c], lds + bo + lofs[c]);
      gp[c] += BK;
    }
  };

  int l15 = lane & 15, l4 = lane >> 4;
  int wr = wid >> 1, wc = wid & 1;
  int soff = (l4 ^ ((l15 >> 1) & 3)) << 3;
  int aoff[4], bhoff[4];
#pragma unroll
  for (int i = 0; i < 4; ++i) {
    int r = wr * 64 + i * 16 + l15;
    int c = wc * 64 + i * 16 + l15;
    aoff[i]  = r * BK + soff;
    bhoff[i] = 4096 + c * BK + soff;
  }

  f32x4 acc[4][4];
#pragma unroll
  for (int m = 0; m < 4; ++m)
#pragma unroll
    for (int n = 0; n < 4; ++n) acc[m][n] = (f32x4){0.f, 0.f, 0.f, 0.f};

  const int nt = klen / BK;   // 16
  stage(0);
  int cur = 0;
  for (int t = 0; t < nt; ++t) {
    if (t + 1 < nt) { stage(cur ? 0 : 8192); VMCNT4; }
    else { VMCNT0; }
    SBAR();
    const short* rb = lds + (cur ? 8192 : 0);
    short8 af[4], bh8[4];
#pragma unroll
    for (int i = 0; i < 4; ++i) {
      af[i]  = *(const short8*)(rb + aoff[i]);
      bh8[i] = *(const short8*)(rb + bhoff[i]);
    }
#pragma unroll
    for (int m = 0; m < 4; ++m)
#pragma unroll
      for (int n = 0; n < 4; ++n)
        acc[m][n] = __builtin_amdgcn_mfma_f32_16x16x32_bf16(af[m], bh8[n], acc[m][n], 0, 0, 0);
    SBAR();
    cur ^= 1;
  }

  short* P = Cpart + (size_t)z * ((size_t)M * N);
#pragma unroll
  for (int n = 0; n < 4; ++n) {
    int col = bn + wc * 64 + n * 16 + l15;
#pragma unroll
    for (int m = 0; m < 4; ++m) {
      int row0 = bm + wr * 64 + m * 16 + (l4 << 2);
#pragma unroll
      for (int r = 0; r < 4; ++r)
        P[(size_t)(row0 + r) * N + col] = f2bf_rne(acc[m][n][r]);
    }
  }
}

// ---------------------------------------------------------------------------
// Merged GEMM2+GEMM3 (both K=256, nt=8): fb<512: q_params -> f32 mean/lv;
// fb>=512: xl/xr -> bf16. Hi/lo B kept (positive-mean A => coherent colsum).
__global__ __launch_bounds__(256) void gemm_dual(
    const short* __restrict__ xe, const short* __restrict__ xd,
    const short* __restrict__ fcH, const short* __restrict__ fcL,
    const short* __restrict__ WlH, const short* __restrict__ WlL,
    const short* __restrict__ WrH, const short* __restrict__ WrL,
    const float* __restrict__ fc_b, const float* __restrict__ bl,
    const float* __restrict__ br,
    float* __restrict__ out_mean, float* __restrict__ out_lv,
    short* __restrict__ xl, short* __restrict__ xr)
{
  __shared__ short lds[2 * 12288];
  const int K = 256;
  int fb = blockIdx.x;
  const short *A, *Bh, *Bl;
  const float* bias;
  int bm, bn, jobB, ldc;
  short* Obf = nullptr;
  float* Of = nullptr;
  if (fb < 512) {
    A = xe; Bh = fcH; Bl = fcL; bias = fc_b;
    bn = (fb & 31) << 7; bm = (fb >> 5) << 7;
    jobB = 0; ldc = 2048; Of = out_mean;
  } else {
    int g = fb - 512, twin = g & 1, t = g >> 1;
    A = xd; Bh = twin ? WrH : WlH; Bl = twin ? WrL : WlL;
    bias = twin ? br : bl;
    bn = (t & 7) << 7; bm = (t >> 3) << 7;
    jobB = 1; ldc = 1024; Obf = twin ? xr : xl;
  }

  int tid = threadIdx.x;
  int lane = tid & 63, wid = tid >> 6;

  const short* gp[6];
  int lofs[6];
  {
    int r4 = lane >> 2;
    int ksw = (lane & 3) ^ ((lane >> 3) & 3);
#pragma unroll
    for (int c = 0; c < 6; ++c) {
      int chunk = wid * 6 + c;
      int p = chunk >> 3, s = chunk & 7;
      int r = (s << 4) + r4;
      const short* bp = (p == 0) ? (A + (size_t)(bm + r) * K)
                      : (p == 1) ? (Bh + (size_t)(bn + r) * K)
                                 : (Bl + (size_t)(bn + r) * K);
      gp[c] = bp + (ksw << 3);
      lofs[c] = (p << 12) + (s << 9);
    }
  }
  auto stage = [&](int bo) {
#pragma unroll
    for (int c = 0; c < 6; ++c) {
      gload_lds16(gp[c], lds + bo + lofs[c]);
      gp[c] += BK;
    }
  };

  int l15 = lane & 15, l4 = lane >> 4;
  int wr = wid >> 1, wc = wid & 1;
  int soff = (l4 ^ ((l15 >> 1) & 3)) << 3;
  int aoff[4], bhoff[4], bloff[4];
#pragma unroll
  for (int i = 0; i < 4; ++i) {
    int r = wr * 64 + i * 16 + l15;
    int c = wc * 64 + i * 16 + l15;
    aoff[i]  = r * BK + soff;
    bhoff[i] = 4096 + c * BK + soff;
    bloff[i] = 8192 + c * BK + soff;
  }

  f32x4 acc[4][4];
#pragma unroll
  for (int m = 0; m < 4; ++m)
#pragma unroll
    for (int n = 0; n < 4; ++n) acc[m][n] = (f32x4){0.f, 0.f, 0.f, 0.f};

  stage(0);
  int cur = 0;
#pragma unroll
  for (int t = 0; t < 8; ++t) {
    if (t + 1 < 8) { stage(cur ? 0 : 12288); VMCNT6; }
    else { VMCNT0; }
    SBAR();
    const short* rb = lds + (cur ? 12288 : 0);
    short8 af[4], bh8[4], bl8[4];
#pragma unroll
    for (int i = 0; i < 4; ++i) {
      af[i]  = *(const short8*)(rb + aoff[i]);
      bh8[i] = *(const short8*)(rb + bhoff[i]);
      bl8[i] = *(const short8*)(rb + bloff[i]);
    }
#pragma unroll
    for (int m = 0; m < 4; ++m)
#pragma unroll
      for (int n = 0; n < 4; ++n) {
        acc[m][n] = __builtin_amdgcn_mfma_f32_16x16x32_bf16(af[m], bh8[n], acc[m][n], 0, 0, 0);
        acc[m][n] = __builtin_amdgcn_mfma_f32_16x16x32_bf16(af[m], bl8[n], acc[m][n], 0, 0, 0);
      }
    SBAR();
    cur ^= 1;
  }

#pragma unroll
  for (int n = 0; n < 4; ++n) {
    int col = bn + wc * 64 + n * 16 + l15;
    float bv = bias[col];
    if (jobB) {
#pragma unroll
      for (int m = 0; m < 4; ++m) {
        int row0 = bm + wr * 64 + m * 16 + (l4 << 2);
#pragma unroll
        for (int r = 0; r < 4; ++r)
          Obf[(size_t)(row0 + r) * ldc + col] = f2bf_rne(acc[m][n][r] + bv);
      }
    } else {
      float* O = Of; int oc = col;
      if (col >= 2048) { O = out_lv; oc = col - 2048; }
#pragma unroll
      for (int m = 0; m < 4; ++m) {
        int row0 = bm + wr * 64 + m * 16 + (l4 << 2);
#pragma unroll
        for (int r = 0; r < 4; ++r)
          O[(size_t)(row0 + r) * ldc + oc] = acc[m][n][r] + bv;
      }
    }
  }
}

// ---------------------------------------------------------------------------
// split-K reduce (16 bf16 slices) + bias + relu -> bf16 planes x_enc / x_dec
__global__ __launch_bounds__(256) void sumrelu_kernel(
    const short* __restrict__ part, const float* __restrict__ b0,
    const float* __restrict__ b1, short* __restrict__ xe,
    short* __restrict__ xd)
{
  int i4 = blockIdx.x * 256 + threadIdx.x;
  size_t S = (size_t)N_NODES * 256;
  size_t base = (size_t)i4 * 4;
  int col = (int)(base & 255);
  float4 b0v = *(const float4*)(b0 + col);
  float4 b1v = *(const float4*)(b1 + col);
  float s0[4] = {}, s1[4] = {};
#pragma unroll
  for (int c = 0; c < 8; ++c) {
    short4 p0 = *(const short4*)(part + (size_t)(2 * c) * S + base);
    short4 p1 = *(const short4*)(part + (size_t)(2 * c + 1) * S + base);
    s0[0] += bf2f(p0.x); s0[1] += bf2f(p0.y); s0[2] += bf2f(p0.z); s0[3] += bf2f(p0.w);
    s1[0] += bf2f(p1.x); s1[1] += bf2f(p1.y); s1[2] += bf2f(p1.z); s1[3] += bf2f(p1.w);
  }
  short4 e, d;
  e.x = f2bf_rne(fmaxf(s0[0] + b0v.x, 0.f));
  e.y = f2bf_rne(fmaxf(s0[1] + b0v.y, 0.f));
  e.z = f2bf_rne(fmaxf(s0[2] + b0v.z, 0.f));
  e.w = f2bf_rne(fmaxf(s0[3] + b0v.w, 0.f));
  d.x = f2bf_rne(fmaxf(s1[0] + b1v.x, 0.f));
  d.y = f2bf_rne(fmaxf(s1[1] + b1v.y, 0.f));
  d.z = f2bf_rne(fmaxf(s1[2] + b1v.z, 0.f));
  d.w = f2bf_rne(fmaxf(s1[3] + b1v.w, 0.f));
  *(short4*)(xe + base) = e;
  *(short4*)(xd + base) = d;
}

// ---------------------------------------------------------------------------
// Mega-B: GATv2 (2048 blocks, bucket-CSR) || zsum (512 blocks).
// Epilogue also accumulates cs_gat (colsum of bf16-rounded gat output) for
// the exact rank-1 csx correction in xrec_sum.
__global__ __launch_bounds__(256) void megaB_kernel(
    const short* __restrict__ xl, const short* __restrict__ xr,
    const float* __restrict__ att, const float* __restrict__ bias,
    const int* __restrict__ csr, const int* __restrict__ cursor,
    short* __restrict__ outp, float* __restrict__ cs_gat,
    const float* __restrict__ mean_in, const float* __restrict__ lv_in,
    const float* __restrict__ eps, float* __restrict__ z,
    float* __restrict__ csz)
{
  __shared__ float xr_s[HH];
  __shared__ float att_s[HH];
  __shared__ float e_s[8 * CHUNK];
  __shared__ int   src_s[CHUNK];
  __shared__ float m_s[8], s_s[8], f_s[8];

  int tid = threadIdx.x;

  if (blockIdx.x >= 2048) {
    int flat = blockIdx.x - 2048;             // 512 blocks
    int c = ((flat & 3) * 256 + tid) * 2;
    int r0 = (flat >> 2) * 16;
    float sx = 0.f, sy = 0.f;
    for (int r = r0; r < r0 + 16; ++r) {
      size_t off = (size_t)r * 2048 + c;
      float2 m = *(const float2*)(mean_in + off);
      float2 v = *(const float2*)(lv_in + off);
      float2 e = *(const float2*)(eps + off);
      float zx = m.x + expf(0.5f * v.x) * e.x;
      float zy = m.y + expf(0.5f * v.y) * e.y;
      *(float2*)(z + off) = make_float2(zx, zy);
      sx += zx; sy += zy;
    }
    atomicAdd(&csz[c], sx);
    atomicAdd(&csz[c + 1], sy);
    return;
  }

  int n = blockIdx.x;
  {
    short4 x4 = ((const short4*)(xr + (size_t)n * HH))[tid];
    xr_s[tid * 4 + 0] = bf2f(x4.x);
    xr_s[tid * 4 + 1] = bf2f(x4.y);
    xr_s[tid * 4 + 2] = bf2f(x4.z);
    xr_s[tid * 4 + 3] = bf2f(x4.w);
  }
  ((float4*)att_s)[tid] = ((const float4*)att)[tid];
  if (tid < 8) { m_s[tid] = -INFINITY; s_s[tid] = 0.f; }
  __syncthreads();

  int beg = n << 7;
  int cnt_total = min(cursor[n], 128);
  int end = beg + cnt_total;
  int ht = tid >> 5;
  float4 acc = make_float4(0.f, 0.f, 0.f, 0.f);

  for (int c0 = beg; c0 < end; c0 += CHUNK) {
    int cnt = min(CHUNK, end - c0);
    if (tid < cnt) src_s[tid] = csr[c0 + tid];
    __syncthreads();

    int wave = tid >> 6, lane = tid & 63;
    int d0 = lane << 4;
    for (int e = wave; e < cnt; e += 4) {
      const short* xlr = xl + (size_t)src_s[e] * HH + d0;
      short8 a0 = *(const short8*)xlr;
      short8 a1 = *(const short8*)(xlr + 8);
      float sum = 0.f;
#pragma unroll
      for (int j = 0; j < 8; ++j) {
        float t = bf2f(a0[j]) + xr_s[d0 + j];
        t = t > 0.f ? t : 0.2f * t;
        sum += t * att_s[d0 + j];
      }
#pragma unroll
      for (int j = 0; j < 8; ++j) {
        float t = bf2f(a1[j]) + xr_s[d0 + 8 + j];
        t = t > 0.f ? t : 0.2f * t;
        sum += t * att_s[d0 + 8 + j];
      }
      sum += __shfl_xor(sum, 1);
      sum += __shfl_xor(sum, 2);
      sum += __shfl_xor(sum, 4);
      if ((lane & 7) == 0) e_s[(lane >> 3) * CHUNK + e] = sum;
    }
    __syncthreads();

    // wave-parallel online-softmax bookkeeping: 32 threads per head
    {
      int h = tid >> 5, i0 = tid & 31;
      float cm = -INFINITY;
      for (int e = i0; e < cnt; e += 32) cm = fmaxf(cm, e_s[h * CHUNK + e]);
#pragma unroll
      for (int m = 1; m < 32; m <<= 1) cm = fmaxf(cm, __shfl_xor(cm, m));
      float m_old = m_s[h];
      float m_new = fmaxf(m_old, cm);
      float csum = 0.f;
      for (int e = i0; e < cnt; e += 32) {
        float p = expf(e_s[h * CHUNK + e] - m_new);
        e_s[h * CHUNK + e] = p;
        csum += p;
      }
#pragma unroll
      for (int m = 1; m < 32; m <<= 1) csum += __shfl_xor(csum, m);
      if (i0 == 0) {
        float f = expf(m_old - m_new);
        s_s[h] = s_s[h] * f + csum;
        m_s[h] = m_new;
        f_s[h] = f;
      }
    }
    __syncthreads();

    float f = f_s[ht];
    acc.x *= f; acc.y *= f; acc.z *= f; acc.w *= f;
    for (int e = 0; e < cnt; ++e) {
      float p = e_s[ht * CHUNK + e];
      short4 v = *(const short4*)(xl + (size_t)src_s[e] * HH + (tid << 2));
      acc.x += p * bf2f(v.x); acc.y += p * bf2f(v.y);
      acc.z += p * bf2f(v.z); acc.w += p * bf2f(v.w);
    }
    __syncthreads();
  }

  float inv = 1.0f / s_s[ht];
  float4 b4 = *(const float4*)(bias + (tid << 2));
  short4 o4;
  o4.x = f2bf_rne(fmaxf(acc.x * inv + b4.x, 0.f));
  o4.y = f2bf_rne(fmaxf(acc.y * inv + b4.y, 0.f));
  o4.z = f2bf_rne(fmaxf(acc.z * inv + b4.z, 0.f));
  o4.w = f2bf_rne(fmaxf(acc.w * inv + b4.w, 0.f));
  *(short4*)(outp + (size_t)n * HH + (tid << 2)) = o4;
  // cs_gat += bf16-rounded output (exactly what gemm_xrec consumes)
  atomicAdd(&cs_gat[tid * 4 + 0], bf2f(o4.x));
  atomicAdd(&cs_gat[tid * 4 + 1], bf2f(o4.y));
  atomicAdd(&cs_gat[tid * 4 + 2], bf2f(o4.z));
  atomicAdd(&cs_gat[tid * 4 + 3], bf2f(o4.w));
}

// ---------------------------------------------------------------------------
// x_rec = part0 + part1 + bias (f32 out), fused csx. grid (4,128).
// by==0 blocks additionally apply the exact rank-1 lo-plane correction:
// csx[c] += sum_k cs_gat[k] * dfL[c][k].
__global__ __launch_bounds__(256) void xrec_sum_kernel(
    const short* __restrict__ part, const float* __restrict__ bias,
    float* __restrict__ xrec, float* __restrict__ csx,
    const float* __restrict__ cs_gat, const short* __restrict__ dfL)
{
  int c = (blockIdx.x * 256 + threadIdx.x) * 2;
  int r0 = blockIdx.y * 16;
  size_t S = (size_t)N_NODES * 2048;
  float2 b = *(const float2*)(bias + c);
  float sx = 0.f, sy = 0.f;
  for (int r = r0; r < r0 + 16; ++r) {
    size_t off = (size_t)r * 2048 + c;
    short2 p0 = *(const short2*)(part + off);
    short2 p1 = *(const short2*)(part + S + off);
    float vx = bf2f(p0.x) + bf2f(p1.x) + b.x;
    float vy = bf2f(p0.y) + bf2f(p1.y) + b.y;
    *(float2*)(xrec + off) = make_float2(vx, vy);
    sx += vx; sy += vy;
  }
  if (blockIdx.y == 0) {
    const short* rw0 = dfL + (size_t)c * 1024;
    const short* rw1 = dfL + (size_t)(c + 1) * 1024;
    float a0 = 0.f, a1 = 0.f;
    for (int k = 0; k < 1024; k += 4) {
      float4 g = *(const float4*)(cs_gat + k);
      short4 w0 = *(const short4*)(rw0 + k);
      short4 w1 = *(const short4*)(rw1 + k);
      a0 += g.x * bf2f(w0.x) + g.y * bf2f(w0.y) + g.z * bf2f(w0.z) + g.w * bf2f(w0.w);
      a1 += g.x * bf2f(w1.x) + g.y * bf2f(w1.y) + g.z * bf2f(w1.z) + g.w * bf2f(w1.w);
    }
    sx += a0; sy += a1;
  }
  atomicAdd(&csx[c], sx);
  atomicAdd(&csx[c + 1], sy);
}

// ---------------------------------------------------------------------------
__global__ __launch_bounds__(256) void final_kernel(
    const float* __restrict__ Ad, const float* __restrict__ Ai,
    const float* __restrict__ gum, const float* __restrict__ csx,
    const float* __restrict__ csz, float* __restrict__ ce_out,
    float* __restrict__ adj_out)
{
  int i = blockIdx.x;
  int tid = threadIdx.x;
  size_t rb = (size_t)i * 2048;

  float vmax = -INFINITY; int vidx = 0;
  for (int j4 = tid; j4 < 512; j4 += 256) {
    float4 ad = *(const float4*)(Ad  + rb + (size_t)j4 * 4);
    float4 ai = *(const float4*)(Ai  + rb + (size_t)j4 * 4);
    float4 g  = *(const float4*)(gum + rb + (size_t)j4 * 4);
    float4 cx = *(const float4*)(csx + (size_t)j4 * 4);
    float4 cz = *(const float4*)(csz + (size_t)j4 * 4);
    float4 ce;
    ce.x = ad.x * cx.x + ai.x * cz.x;
    ce.y = ad.y * cx.y + ai.y * cz.y;
    ce.z = ad.z * cx.z + ai.z * cz.z;
    ce.w = ad.w * cx.w + ai.w * cz.w;
    *(float4*)(ce_out + rb + (size_t)j4 * 4) = ce;
    int j = j4 * 4;
    float l;
    l = (ce.x + g.x) * 2.0f; if (l > vmax) { vmax = l; vidx = j; }
    l = (ce.y + g.y) * 2.0f; if (l > vmax) { vmax = l; vidx = j + 1; }
    l = (ce.z + g.z) * 2.0f; if (l > vmax) { vmax = l; vidx = j + 2; }
    l = (ce.w + g.w) * 2.0f; if (l > vmax) { vmax = l; vidx = j + 3; }
  }
  for (int m = 1; m < 64; m <<= 1) {
    float ov = __shfl_xor(vmax, m);
    int   oi = __shfl_xor(vidx, m);
    if (ov > vmax || (ov == vmax && oi < vidx)) { vmax = ov; vidx = oi; }
  }
  __shared__ float wm[4];
  __shared__ int   wi[4];
  __shared__ int   amax;
  int lane = tid & 63, wave = tid >> 6;
  if (lane == 0) { wm[wave] = vmax; wi[wave] = vidx; }
  __syncthreads();
  if (tid == 0) {
    float bv = wm[0]; int bi = wi[0];
    for (int w = 1; w < 4; ++w)
      if (wm[w] > bv || (wm[w] == bv && wi[w] < bi)) { bv = wm[w]; bi = wi[w]; }
    amax = bi;
  }
  __syncthreads();
  int am = amax;
  for (int j4 = tid; j4 < 512; j4 += 256) {
    int j = j4 * 4;
    float4 o;
    o.x = (j     == am) ? 1.f : 0.f;
    o.y = (j + 1 == am) ? 1.f : 0.f;
    o.z = (j + 2 == am) ? 1.f : 0.f;
    o.w = (j + 3 == am) ? 1.f : 0.f;
    *(float4*)(adj_out + rb + (size_t)j4 * 4) = o;
  }
}

// ---------------------------------------------------------------------------
extern "C" void kernel_launch(void* const* d_in, const int* in_sizes, int n_in,
                              void* d_out, int out_size, void* d_ws, size_t ws_size,
                              hipStream_t stream) {
  (void)in_sizes; (void)n_in; (void)out_size; (void)ws_size;

  const int*   edge_index = (const int*)d_in[4];   // [2, E]
  const float* lagged     = (const float*)d_in[5];
  const float* eps        = (const float*)d_in[6];
  const float* gumbel     = (const float*)d_in[7];
  const float* enc_Wv     = (const float*)d_in[22];
  const float* enc_bv     = (const float*)d_in[23];
  const float* enc_fc_W   = (const float*)d_in[24];
  const float* enc_fc_b   = (const float*)d_in[25];
  const float* dec_Wv     = (const float*)d_in[30];
  const float* dec_bv     = (const float*)d_in[31];
  const float* gat_Wl     = (const float*)d_in[32];
  const float* gat_bl     = (const float*)d_in[33];
  const float* gat_Wr     = (const float*)d_in[34];
  const float* gat_br     = (const float*)d_in[35];
  const float* gat_att    = (const float*)d_in[36];
  const float* gat_bias   = (const float*)d_in[37];
  const float* dec_fc_W   = (const float*)d_in[38];
  const float* dec_fc_b   = (const float*)d_in[39];
  const float* A_dir      = (const float*)d_in[40];
  const float* A_ind      = (const float*)d_in[41];

  float* out      = (float*)d_out;
  float* out_z    = out;
  float* out_mean = out + (size_t)NL;
  float* out_lv   = out + 2 * (size_t)NL;
  float* out_xrec = out + 3 * (size_t)NL;
  float* out_ce   = out + 4 * (size_t)NL;
  float* out_adj  = out + 5 * (size_t)NL;

  char* ws = (char*)d_ws;
  short* lw_bf = (short*)(ws);                                    //  8 MB
  short* WvH0  = (short*)(ws + ((size_t) 8 << 20));
  short* WvH1  = (short*)(ws + ((size_t)10 << 20));
  short* fcH   = (short*)(ws + ((size_t)12 << 20));               //  2 MB
  short* fcL   = (short*)(ws + ((size_t)14 << 20));
  short* WlH   = (short*)(ws + ((size_t)16 << 20));               // .5 MB
  short* WlL   = (short*)(ws + ((size_t)16 << 20) + (512u << 10));
  short* WrH   = (short*)(ws + ((size_t)17 << 20));
  short* WrL   = (short*)(ws + ((size_t)17 << 20) + (512u << 10));
  short* dfH   = (short*)(ws + ((size_t)18 << 20));               //  4 MB
  short* dfL   = (short*)(ws + ((size_t)22 << 20));
  short* xe_bf = (short*)(ws + ((size_t)26 << 20));               //  1 MB
  short* xd_bf = (short*)(ws + ((size_t)27 << 20));
  short* xl    = (short*)(ws + ((size_t)28 << 20));               //  4 MB
  short* xr    = (short*)(ws + ((size_t)32 << 20));               //  4 MB
  short* gt_bf = (short*)(ws + ((size_t)44 << 20));               //  4 MB
  short* part  = (short*)(ws + ((size_t)48 << 20));               // 16 MB
  int*   cursor = (int*) (ws + ((size_t)64 << 20));               //  8 KB
  int*   csr    = (int*) (ws + ((size_t)64 << 20) + (64u << 10)); //  1 MB
  float* csx    = (float*)(ws + ((size_t)66 << 20));
  float* csz    = (float*)(ws + ((size_t)66 << 20) + (16u << 10));
  float* cs_gat = (float*)(ws + ((size_t)66 << 20) + (32u << 10));

  const int* e_src = edge_index;
  const int* e_dst = edge_index + NE;

  // Mega-A: lw || encWv/decWv H-plane split || init (cursor/csx/csz/cs_gat)
  {
    WCfg2 c2;
    c2.c[0] = { enc_Wv, WvH0, nullptr, 2048, 256, 512 };
    c2.c[1] = { dec_Wv, WvH1, nullptr, 2048, 256, 512 };
    megaA_kernel<<<3080, 256, 0, stream>>>(lagged, lw_bf, c2,
                                           cursor, csx, csz, cs_gat);
  }

  // Mega-C: encV/decV GEMM || remaining weight splits || bucket-CSR fill
  {
    WCfg4 c4;
    c4.c[0] = { enc_fc_W, fcH, fcL, 256,  4096, 1024 };
    c4.c[1] = { gat_Wl,   WlH, WlL, 256,  1024, 256  };
    c4.c[2] = { gat_Wr,   WrH, WrL, 256,  1024, 256  };
    c4.c[3] = { dec_fc_W, dfH, dfL, 1024, 2048, 2048 };
    megaC_kernel<<<4360, 256, 0, stream>>>(
        lw_bf, WvH0, WvH1, part, c4, e_src, e_dst, cursor, csr);
  }

  // split-K reduce -> x_enc/x_dec (bf16)
  sumrelu_kernel<<<512, 256, 0, stream>>>(part, enc_bv, dec_bv, xe_bf, xd_bf);

  // merged: q_params GEMM (mean/lv) + xl/xr twin GEMM in one dispatch
  gemm_dual<<<768, 256, 0, stream>>>(
      xe_bf, xd_bf, fcH, fcL, WlH, WlL, WrH, WrL,
      enc_fc_b, gat_bl, gat_br, out_mean, out_lv, xl, xr);

  // Mega-B: GATv2 (+cs_gat) || zsum (z + csz)
  megaB_kernel<<<2560, 256, 0, stream>>>(
      xl, xr, gat_att, gat_bias, csr, cursor, gt_bf, cs_gat,
      out_mean, out_lv, eps, out_z, csz);

  // x_rec GEMM: hi-plane only, split-K x2 (lo-plane csx restored exactly)
  gemm_xrec<<<dim3(16, 16, 2), 256, 0, stream>>>(gt_bf, dfH, part);
  xrec_sum_kernel<<<dim3(4, 128), 256, 0, stream>>>(
      part, dec_fc_b, out_xrec, csx, cs_gat, dfL);

  // causal effect + hard gumbel one-hot
  final_kernel<<<N_NODES, 256, 0, stream>>>(A_dir, A_ind, gumbel, csx, csz,
                                            out_ce, out_adj);
}

// Round 12
// 217.838 us; speedup vs baseline: 1.7678x; 1.7678x over previous
//
#include <hip/hip_runtime.h>
#include <hip/hip_bf16.h>
#include <math.h>

#define N_NODES 2048
#define DIN     2048
#define HH      1024
#define LAGS    12
#define NE      65536
#define NL      (2048 * 2048)
#define CHUNK   128

#define BM 128
#define BN 128
#define BK 32

typedef __attribute__((ext_vector_type(8))) short short8;
typedef __attribute__((ext_vector_type(4))) float f32x4;

static __device__ __forceinline__ short f2bf_rne(float x) {
  union { float f; unsigned u; } c; c.f = x;
  unsigned u = c.u;
  unsigned r = (u + 0x7fffu + ((u >> 16) & 1u)) >> 16;
  return (short)r;
}
static __device__ __forceinline__ float bf2f(short h) {
  union { unsigned u; float f; } c; c.u = ((unsigned)(unsigned short)h) << 16;
  return c.f;
}

typedef __attribute__((address_space(3))) unsigned int as3_u32;
typedef const __attribute__((address_space(1))) unsigned int as1_u32c;
static __device__ __forceinline__ void gload_lds16(const void* g, void* l) {
  __builtin_amdgcn_global_load_lds((as1_u32c*)g, (as3_u32*)l, 16, 0, 0);
}

// vmcnt is PER-WAVE: each wave issues CPW global_load_lds per stage(); in
// steady state 2*CPW are outstanding; waiting for the previous tile = CPW.
#define VMCNT6  asm volatile("s_waitcnt vmcnt(6)" ::: "memory")
#define VMCNT4  asm volatile("s_waitcnt vmcnt(4)" ::: "memory")
#define VMCNT0  asm volatile("s_waitcnt vmcnt(0)" ::: "memory")
#define SBAR()  do { asm volatile("" ::: "memory"); __builtin_amdgcn_s_barrier(); \
                     asm volatile("" ::: "memory"); } while (0)

struct WCfg { const float* W; short* H; short* L; int K; int N; int nb; };
struct WCfg2 { WCfg c[2]; };
struct WCfg4 { WCfg c[4]; };

// weight transpose + hi/lo split of one 32x32 tile (L optional)
static __device__ __forceinline__ void wsplit_tile(
    const WCfg& cf, int local, int tid, float t[32][33])
{
  const float* W = cf.W;
  short* H = cf.H;
  short* L = cf.L;
  int K = cf.K, N = cf.N;
  int nbx = N >> 5;
  int bx = local % nbx, by = local / nbx;
  int tx = tid & 31, ty = tid >> 5;
  int c0 = bx << 5, k0 = by << 5;
#pragma unroll
  for (int j = 0; j < 4; ++j)
    t[ty + 8 * j][tx] = W[(size_t)(k0 + ty + 8 * j) * N + c0 + tx];
  __syncthreads();
#pragma unroll
  for (int j = 0; j < 4; ++j) {
    int c = ty + 8 * j;
    float x = t[tx][c];
    short h = f2bf_rne(x);
    size_t off = (size_t)(c0 + c) * K + k0 + tx;
    H[off] = h;
    if (L) L[off] = f2bf_rne(x - bf2f(h));
  }
}

// ---------------------------------------------------------------------------
// Mega-A: lw (2048) || encWv/decWv H-plane split (1024) || init (8).
__global__ __launch_bounds__(256) void megaA_kernel(
    const float* __restrict__ lagged, short* __restrict__ lw, WCfg2 cfgs,
    int* __restrict__ cursor, float* __restrict__ csx,
    float* __restrict__ csz, float* __restrict__ cs_gat)
{
  __shared__ float t[32][33];
  int bid = blockIdx.x;
  int tid = threadIdx.x;

  if (bid < 2048) {
    int idx = bid * 256 + tid;
    int n = idx >> 8, c8 = idx & 255;
    const float* base = lagged + (size_t)n * (LAGS * DIN) + (size_t)c8 * 8;
    float a[8] = {};
#pragma unroll
    for (int l = 0; l < LAGS; ++l) {
      float w = (float)((double)(LAGS - l) / 78.0);
      float4 v0 = *(const float4*)(base + (size_t)l * DIN);
      float4 v1 = *(const float4*)(base + (size_t)l * DIN + 4);
      a[0] += w * v0.x; a[1] += w * v0.y; a[2] += w * v0.z; a[3] += w * v0.w;
      a[4] += w * v1.x; a[5] += w * v1.y; a[6] += w * v1.z; a[7] += w * v1.w;
    }
    short8 h;
#pragma unroll
    for (int j = 0; j < 8; ++j) h[j] = f2bf_rne(a[j]);
    *(short8*)(lw + (size_t)idx * 8) = h;
  } else if (bid < 3072) {
    int wb = bid - 2048;
    int i = (wb >= cfgs.c[0].nb) ? 1 : 0;
    int local = wb - (i ? cfgs.c[0].nb : 0);
    wsplit_tile(cfgs.c[i], local, tid, t);
  } else {
    int i = (bid - 3072) * 256 + tid;   // 8 blocks -> 2048
    cursor[i] = 0; csx[i] = 0.f; csz[i] = 0.f;
    if (i < 1024) cs_gat[i] = 0.f;
  }
}

// ---------------------------------------------------------------------------
// Mega-C: encV/decV GEMM (512 blocks, single-plane B, split-K x8) ||
// fc/Wl/Wr/dec_fc weight splits (3584) || bucket-CSR fill (264).
__global__ __launch_bounds__(256) void megaC_kernel(
    const short* __restrict__ A, const short* __restrict__ Bh0,
    const short* __restrict__ Bh1, short* __restrict__ Cpart,
    WCfg4 cfgs,
    const int* __restrict__ esrc, const int* __restrict__ edst,
    int* __restrict__ cursor, int* __restrict__ csr)
{
  __shared__ char smem[32768];
  int fb = blockIdx.x;
  int tid = threadIdx.x;

  if (fb < 512) {
    // ---- gemm (2-plane): M=2048 N=256 K=2048, klen=256, ntwin=2 ----
    short* lds = (short*)smem;
    const int K = 2048, N = 256, M = 2048, klen = 256;
    int lane = tid & 63, wid = tid >> 6;
    int bn = (fb & 1) * BN;
    int bm = ((fb >> 1) & 15) * BM;
    int z = fb >> 5;
    int twin = z & 1;
    int kb = (z >> 1) * klen;
    const short* Bh = twin ? Bh1 : Bh0;

    const short* gp[4];
    int lofs[4];
    {
      int r4 = lane >> 2;
      int ksw = (lane & 3) ^ ((lane >> 3) & 3);
#pragma unroll
      for (int c = 0; c < 4; ++c) {
        int chunk = wid * 4 + c;
        int p = chunk >> 3, s = chunk & 7;
        int r = (s << 4) + r4;
        const short* bp = (p == 0) ? (A + (size_t)(bm + r) * K)
                                   : (Bh + (size_t)(bn + r) * K);
        gp[c] = bp + kb + (ksw << 3);
        lofs[c] = (p << 12) + (s << 9);
      }
    }
    auto stage = [&](int bo) {
#pragma unroll
      for (int c = 0; c < 4; ++c) {
        gload_lds16(gp[c], lds + bo + lofs[c]);
        gp[c] += BK;
      }
    };

    int l15 = lane & 15, l4 = lane >> 4;
    int wr = wid >> 1, wc = wid & 1;
    int soff = (l4 ^ ((l15 >> 1) & 3)) << 3;
    int aoff[4], bhoff[4];
#pragma unroll
    for (int i = 0; i < 4; ++i) {
      int r = wr * 64 + i * 16 + l15;
      int c = wc * 64 + i * 16 + l15;
      aoff[i]  = r * BK + soff;
      bhoff[i] = 4096 + c * BK + soff;
    }

    f32x4 acc[4][4];
#pragma unroll
    for (int m = 0; m < 4; ++m)
#pragma unroll
      for (int n = 0; n < 4; ++n) acc[m][n] = (f32x4){0.f, 0.f, 0.f, 0.f};

    stage(0);
    int cur = 0;
#pragma unroll
    for (int t = 0; t < 8; ++t) {
      if (t + 1 < 8) { stage(cur ? 0 : 8192); VMCNT4; }
      else { VMCNT0; }
      SBAR();
      const short* rb = lds + (cur ? 8192 : 0);
      short8 af[4], bh8[4];
#pragma unroll
      for (int i = 0; i < 4; ++i) {
        af[i]  = *(const short8*)(rb + aoff[i]);
        bh8[i] = *(const short8*)(rb + bhoff[i]);
      }
#pragma unroll
      for (int m = 0; m < 4; ++m)
#pragma unroll
        for (int n = 0; n < 4; ++n)
          acc[m][n] = __builtin_amdgcn_mfma_f32_16x16x32_bf16(af[m], bh8[n], acc[m][n], 0, 0, 0);
      SBAR();
      cur ^= 1;
    }

    short* P = Cpart + (size_t)z * ((size_t)M * N);
#pragma unroll
    for (int n = 0; n < 4; ++n) {
      int col = bn + wc * 64 + n * 16 + l15;
#pragma unroll
      for (int m = 0; m < 4; ++m) {
        int row0 = bm + wr * 64 + m * 16 + (l4 << 2);
#pragma unroll
        for (int r = 0; r < 4; ++r)
          P[(size_t)(row0 + r) * N + col] = f2bf_rne(acc[m][n][r]);
      }
    }
  } else if (fb < 4096) {
    // ---- weight transpose + hi/lo split (fc, Wl, Wr, dec_fc) ----
    float (*t)[33] = (float(*)[33])smem;
    int wb = fb - 512;
    int i = 0, base = 0;
    while (i < 3 && wb >= base + cfgs.c[i].nb) { base += cfgs.c[i].nb; ++i; }
    wsplit_tile(cfgs.c[i], wb - base, tid, t);
  } else {
    // ---- bucket-CSR fill: 128 slots/node; max in-degree ~52 << 128 ----
    int i = (fb - 4096) * 256 + tid;
    if (i < NE) {
      int d = edst[i];
      int p = atomicAdd(&cursor[d], 1);
      if (p < 128) csr[(d << 7) + p] = esrc[i];
    } else if (i < NE + N_NODES) {
      int nn = i - NE;
      int p = atomicAdd(&cursor[nn], 1);
      if (p < 128) csr[(nn << 7) + p] = nn;   // self-loop
    }
  }
}

// ---------------------------------------------------------------------------
// x_rec GEMM: single-plane B (hi only), split-K x2 -> bf16 partials.
// bn==0 blocks additionally colsum their [128 rows x 512 k] patch of A
// (gt_bf) into cs_gat — 16-way atomic contention max — for the exact
// rank-1 lo-plane csx correction in xrec_sum.
// M=2048, N=2048, K=1024, klen=512. grid (16,16,2).
__global__ __launch_bounds__(256) void gemm_xrec(
    const short* __restrict__ A, const short* __restrict__ Bh,
    short* __restrict__ Cpart, float* __restrict__ cs_gat)
{
  __shared__ short lds[2 * 8192];
  const int K = 1024, N = 2048, M = 2048, klen = 512;
  int tid = threadIdx.x;
  int lane = tid & 63, wid = tid >> 6;
  int bn = blockIdx.x * BN, bm = blockIdx.y * BM;
  int z = blockIdx.z;
  int kb = z * klen;

  const short* gp[4];
  int lofs[4];
  {
    int r4 = lane >> 2;
    int ksw = (lane & 3) ^ ((lane >> 3) & 3);
#pragma unroll
    for (int c = 0; c < 4; ++c) {
      int chunk = wid * 4 + c;
      int p = chunk >> 3, s = chunk & 7;
      int r = (s << 4) + r4;
      const short* bp = (p == 0) ? (A + (size_t)(bm + r) * K)
                                 : (Bh + (size_t)(bn + r) * K);
      gp[c] = bp + kb + (ksw << 3);
      lofs[c] = (p << 12) + (s << 9);
    }
  }
  auto stage = [&](int bo) {
#pragma unroll
    for (int c = 0; c < 4; ++c) {
      gload_lds16(gp[c], lds + bo + lofs[c]);
      gp[c] += BK;
    }
  };

  int l15 = lane & 15, l4 = lane >> 4;
  int wr = wid >> 1, wc = wid & 1;
  int soff = (l4 ^ ((l15 >> 1) & 3)) << 3;
  int aoff[4], bhoff[4];
#pragma unroll
  for (int i = 0; i < 4; ++i) {
    int r = wr * 64 + i * 16 + l15;
    int c = wc * 64 + i * 16 + l15;
    aoff[i]  = r * BK + soff;
    bhoff[i] = 4096 + c * BK + soff;
  }

  f32x4 acc[4][4];
#pragma unroll
  for (int m = 0; m < 4; ++m)
#pragma unroll
    for (int n = 0; n < 4; ++n) acc[m][n] = (f32x4){0.f, 0.f, 0.f, 0.f};

  const int nt = klen / BK;   // 16
  stage(0);
  int cur = 0;
  for (int t = 0; t < nt; ++t) {
    if (t + 1 < nt) { stage(cur ? 0 : 8192); VMCNT4; }
    else { VMCNT0; }
    SBAR();
    const short* rb = lds + (cur ? 8192 : 0);
    short8 af[4], bh8[4];
#pragma unroll
    for (int i = 0; i < 4; ++i) {
      af[i]  = *(const short8*)(rb + aoff[i]);
      bh8[i] = *(const short8*)(rb + bhoff[i]);
    }
#pragma unroll
    for (int m = 0; m < 4; ++m)
#pragma unroll
      for (int n = 0; n < 4; ++n)
        acc[m][n] = __builtin_amdgcn_mfma_f32_16x16x32_bf16(af[m], bh8[n], acc[m][n], 0, 0, 0);
    SBAR();
    cur ^= 1;
  }

  short* P = Cpart + (size_t)z * ((size_t)M * N);
#pragma unroll
  for (int n = 0; n < 4; ++n) {
    int col = bn + wc * 64 + n * 16 + l15;
#pragma unroll
    for (int m = 0; m < 4; ++m) {
      int row0 = bm + wr * 64 + m * 16 + (l4 << 2);
#pragma unroll
      for (int r = 0; r < 4; ++r)
        P[(size_t)(row0 + r) * N + col] = f2bf_rne(acc[m][n][r]);
    }
  }

  // cs_gat colsum epilogue (bn==0 blocks tile rows x K exactly once):
  // thread sums 2 k-columns over this block's 128 rows (gt_bf is L2-hot).
  if (blockIdx.x == 0) {
    int k0 = kb + tid * 2;
    float s0 = 0.f, s1 = 0.f;
    const short* Ar = A + (size_t)bm * K + k0;
    for (int r = 0; r < 128; ++r) {
      short2 v = *(const short2*)(Ar + (size_t)r * K);
      s0 += bf2f(v.x);
      s1 += bf2f(v.y);
    }
    atomicAdd(&cs_gat[k0], s0);
    atomicAdd(&cs_gat[k0 + 1], s1);
  }
}

// ---------------------------------------------------------------------------
// Merged GEMM2+GEMM3 (both K=256, nt=8): fb<512: q_params -> f32 mean/lv;
// fb>=512: xl/xr -> bf16. Hi/lo B kept (positive-mean A => coherent colsum).
__global__ __launch_bounds__(256) void gemm_dual(
    const short* __restrict__ xe, const short* __restrict__ xd,
    const short* __restrict__ fcH, const short* __restrict__ fcL,
    const short* __restrict__ WlH, const short* __restrict__ WlL,
    const short* __restrict__ WrH, const short* __restrict__ WrL,
    const float* __restrict__ fc_b, const float* __restrict__ bl,
    const float* __restrict__ br,
    float* __restrict__ out_mean, float* __restrict__ out_lv,
    short* __restrict__ xl, short* __restrict__ xr)
{
  __shared__ short lds[2 * 12288];
  const int K = 256;
  int fb = blockIdx.x;
  const short *A, *Bh, *Bl;
  const float* bias;
  int bm, bn, jobB, ldc;
  short* Obf = nullptr;
  float* Of = nullptr;
  if (fb < 512) {
    A = xe; Bh = fcH; Bl = fcL; bias = fc_b;
    bn = (fb & 31) << 7; bm = (fb >> 5) << 7;
    jobB = 0; ldc = 2048; Of = out_mean;
  } else {
    int g = fb - 512, twin = g & 1, t = g >> 1;
    A = xd; Bh = twin ? WrH : WlH; Bl = twin ? WrL : WlL;
    bias = twin ? br : bl;
    bn = (t & 7) << 7; bm = (t >> 3) << 7;
    jobB = 1; ldc = 1024; Obf = twin ? xr : xl;
  }

  int tid = threadIdx.x;
  int lane = tid & 63, wid = tid >> 6;

  const short* gp[6];
  int lofs[6];
  {
    int r4 = lane >> 2;
    int ksw = (lane & 3) ^ ((lane >> 3) & 3);
#pragma unroll
    for (int c = 0; c < 6; ++c) {
      int chunk = wid * 6 + c;
      int p = chunk >> 3, s = chunk & 7;
      int r = (s << 4) + r4;
      const short* bp = (p == 0) ? (A + (size_t)(bm + r) * K)
                      : (p == 1) ? (Bh + (size_t)(bn + r) * K)
                                 : (Bl + (size_t)(bn + r) * K);
      gp[c] = bp + (ksw << 3);
      lofs[c] = (p << 12) + (s << 9);
    }
  }
  auto stage = [&](int bo) {
#pragma unroll
    for (int c = 0; c < 6; ++c) {
      gload_lds16(gp[c], lds + bo + lofs[c]);
      gp[c] += BK;
    }
  };

  int l15 = lane & 15, l4 = lane >> 4;
  int wr = wid >> 1, wc = wid & 1;
  int soff = (l4 ^ ((l15 >> 1) & 3)) << 3;
  int aoff[4], bhoff[4], bloff[4];
#pragma unroll
  for (int i = 0; i < 4; ++i) {
    int r = wr * 64 + i * 16 + l15;
    int c = wc * 64 + i * 16 + l15;
    aoff[i]  = r * BK + soff;
    bhoff[i] = 4096 + c * BK + soff;
    bloff[i] = 8192 + c * BK + soff;
  }

  f32x4 acc[4][4];
#pragma unroll
  for (int m = 0; m < 4; ++m)
#pragma unroll
    for (int n = 0; n < 4; ++n) acc[m][n] = (f32x4){0.f, 0.f, 0.f, 0.f};

  stage(0);
  int cur = 0;
#pragma unroll
  for (int t = 0; t < 8; ++t) {
    if (t + 1 < 8) { stage(cur ? 0 : 12288); VMCNT6; }
    else { VMCNT0; }
    SBAR();
    const short* rb = lds + (cur ? 12288 : 0);
    short8 af[4], bh8[4], bl8[4];
#pragma unroll
    for (int i = 0; i < 4; ++i) {
      af[i]  = *(const short8*)(rb + aoff[i]);
      bh8[i] = *(const short8*)(rb + bhoff[i]);
      bl8[i] = *(const short8*)(rb + bloff[i]);
    }
#pragma unroll
    for (int m = 0; m < 4; ++m)
#pragma unroll
      for (int n = 0; n < 4; ++n) {
        acc[m][n] = __builtin_amdgcn_mfma_f32_16x16x32_bf16(af[m], bh8[n], acc[m][n], 0, 0, 0);
        acc[m][n] = __builtin_amdgcn_mfma_f32_16x16x32_bf16(af[m], bl8[n], acc[m][n], 0, 0, 0);
      }
    SBAR();
    cur ^= 1;
  }

#pragma unroll
  for (int n = 0; n < 4; ++n) {
    int col = bn + wc * 64 + n * 16 + l15;
    float bv = bias[col];
    if (jobB) {
#pragma unroll
      for (int m = 0; m < 4; ++m) {
        int row0 = bm + wr * 64 + m * 16 + (l4 << 2);
#pragma unroll
        for (int r = 0; r < 4; ++r)
          Obf[(size_t)(row0 + r) * ldc + col] = f2bf_rne(acc[m][n][r] + bv);
      }
    } else {
      float* O = Of; int oc = col;
      if (col >= 2048) { O = out_lv; oc = col - 2048; }
#pragma unroll
      for (int m = 0; m < 4; ++m) {
        int row0 = bm + wr * 64 + m * 16 + (l4 << 2);
#pragma unroll
        for (int r = 0; r < 4; ++r)
          O[(size_t)(row0 + r) * ldc + oc] = acc[m][n][r] + bv;
      }
    }
  }
}

// ---------------------------------------------------------------------------
// split-K reduce (16 bf16 slices) + bias + relu -> bf16 planes x_enc / x_dec
__global__ __launch_bounds__(256) void sumrelu_kernel(
    const short* __restrict__ part, const float* __restrict__ b0,
    const float* __restrict__ b1, short* __restrict__ xe,
    short* __restrict__ xd)
{
  int i4 = blockIdx.x * 256 + threadIdx.x;
  size_t S = (size_t)N_NODES * 256;
  size_t base = (size_t)i4 * 4;
  int col = (int)(base & 255);
  float4 b0v = *(const float4*)(b0 + col);
  float4 b1v = *(const float4*)(b1 + col);
  float s0[4] = {}, s1[4] = {};
#pragma unroll
  for (int c = 0; c < 8; ++c) {
    short4 p0 = *(const short4*)(part + (size_t)(2 * c) * S + base);
    short4 p1 = *(const short4*)(part + (size_t)(2 * c + 1) * S + base);
    s0[0] += bf2f(p0.x); s0[1] += bf2f(p0.y); s0[2] += bf2f(p0.z); s0[3] += bf2f(p0.w);
    s1[0] += bf2f(p1.x); s1[1] += bf2f(p1.y); s1[2] += bf2f(p1.z); s1[3] += bf2f(p1.w);
  }
  short4 e, d;
  e.x = f2bf_rne(fmaxf(s0[0] + b0v.x, 0.f));
  e.y = f2bf_rne(fmaxf(s0[1] + b0v.y, 0.f));
  e.z = f2bf_rne(fmaxf(s0[2] + b0v.z, 0.f));
  e.w = f2bf_rne(fmaxf(s0[3] + b0v.w, 0.f));
  d.x = f2bf_rne(fmaxf(s1[0] + b1v.x, 0.f));
  d.y = f2bf_rne(fmaxf(s1[1] + b1v.y, 0.f));
  d.z = f2bf_rne(fmaxf(s1[2] + b1v.z, 0.f));
  d.w = f2bf_rne(fmaxf(s1[3] + b1v.w, 0.f));
  *(short4*)(xe + base) = e;
  *(short4*)(xd + base) = d;
}

// ---------------------------------------------------------------------------
// Mega-B: GATv2 (2048 blocks, bucket-CSR) || zsum (512 blocks).
// (cs_gat accumulation moved to gemm_xrec — the 2048-way atomic contention
// here was round-11's 185 µs regression.)
__global__ __launch_bounds__(256) void megaB_kernel(
    const short* __restrict__ xl, const short* __restrict__ xr,
    const float* __restrict__ att, const float* __restrict__ bias,
    const int* __restrict__ csr, const int* __restrict__ cursor,
    short* __restrict__ outp,
    const float* __restrict__ mean_in, const float* __restrict__ lv_in,
    const float* __restrict__ eps, float* __restrict__ z,
    float* __restrict__ csz)
{
  __shared__ float xr_s[HH];
  __shared__ float att_s[HH];
  __shared__ float e_s[8 * CHUNK];
  __shared__ int   src_s[CHUNK];
  __shared__ float m_s[8], s_s[8], f_s[8];

  int tid = threadIdx.x;

  if (blockIdx.x >= 2048) {
    int flat = blockIdx.x - 2048;             // 512 blocks
    int c = ((flat & 3) * 256 + tid) * 2;
    int r0 = (flat >> 2) * 16;
    float sx = 0.f, sy = 0.f;
    for (int r = r0; r < r0 + 16; ++r) {
      size_t off = (size_t)r * 2048 + c;
      float2 m = *(const float2*)(mean_in + off);
      float2 v = *(const float2*)(lv_in + off);
      float2 e = *(const float2*)(eps + off);
      float zx = m.x + expf(0.5f * v.x) * e.x;
      float zy = m.y + expf(0.5f * v.y) * e.y;
      *(float2*)(z + off) = make_float2(zx, zy);
      sx += zx; sy += zy;
    }
    atomicAdd(&csz[c], sx);
    atomicAdd(&csz[c + 1], sy);
    return;
  }

  int n = blockIdx.x;
  {
    short4 x4 = ((const short4*)(xr + (size_t)n * HH))[tid];
    xr_s[tid * 4 + 0] = bf2f(x4.x);
    xr_s[tid * 4 + 1] = bf2f(x4.y);
    xr_s[tid * 4 + 2] = bf2f(x4.z);
    xr_s[tid * 4 + 3] = bf2f(x4.w);
  }
  ((float4*)att_s)[tid] = ((const float4*)att)[tid];
  if (tid < 8) { m_s[tid] = -INFINITY; s_s[tid] = 0.f; }
  __syncthreads();

  int beg = n << 7;
  int cnt_total = min(cursor[n], 128);
  int end = beg + cnt_total;
  int ht = tid >> 5;
  float4 acc = make_float4(0.f, 0.f, 0.f, 0.f);

  for (int c0 = beg; c0 < end; c0 += CHUNK) {
    int cnt = min(CHUNK, end - c0);
    if (tid < cnt) src_s[tid] = csr[c0 + tid];
    __syncthreads();

    int wave = tid >> 6, lane = tid & 63;
    int d0 = lane << 4;
    for (int e = wave; e < cnt; e += 4) {
      const short* xlr = xl + (size_t)src_s[e] * HH + d0;
      short8 a0 = *(const short8*)xlr;
      short8 a1 = *(const short8*)(xlr + 8);
      float sum = 0.f;
#pragma unroll
      for (int j = 0; j < 8; ++j) {
        float t = bf2f(a0[j]) + xr_s[d0 + j];
        t = t > 0.f ? t : 0.2f * t;
        sum += t * att_s[d0 + j];
      }
#pragma unroll
      for (int j = 0; j < 8; ++j) {
        float t = bf2f(a1[j]) + xr_s[d0 + 8 + j];
        t = t > 0.f ? t : 0.2f * t;
        sum += t * att_s[d0 + 8 + j];
      }
      sum += __shfl_xor(sum, 1);
      sum += __shfl_xor(sum, 2);
      sum += __shfl_xor(sum, 4);
      if ((lane & 7) == 0) e_s[(lane >> 3) * CHUNK + e] = sum;
    }
    __syncthreads();

    // wave-parallel online-softmax bookkeeping: 32 threads per head
    {
      int h = tid >> 5, i0 = tid & 31;
      float cm = -INFINITY;
      for (int e = i0; e < cnt; e += 32) cm = fmaxf(cm, e_s[h * CHUNK + e]);
#pragma unroll
      for (int m = 1; m < 32; m <<= 1) cm = fmaxf(cm, __shfl_xor(cm, m));
      float m_old = m_s[h];
      float m_new = fmaxf(m_old, cm);
      float csum = 0.f;
      for (int e = i0; e < cnt; e += 32) {
        float p = expf(e_s[h * CHUNK + e] - m_new);
        e_s[h * CHUNK + e] = p;
        csum += p;
      }
#pragma unroll
      for (int m = 1; m < 32; m <<= 1) csum += __shfl_xor(csum, m);
      if (i0 == 0) {
        float f = expf(m_old - m_new);
        s_s[h] = s_s[h] * f + csum;
        m_s[h] = m_new;
        f_s[h] = f;
      }
    }
    __syncthreads();

    float f = f_s[ht];
    acc.x *= f; acc.y *= f; acc.z *= f; acc.w *= f;
    for (int e = 0; e < cnt; ++e) {
      float p = e_s[ht * CHUNK + e];
      short4 v = *(const short4*)(xl + (size_t)src_s[e] * HH + (tid << 2));
      acc.x += p * bf2f(v.x); acc.y += p * bf2f(v.y);
      acc.z += p * bf2f(v.z); acc.w += p * bf2f(v.w);
    }
    __syncthreads();
  }

  float inv = 1.0f / s_s[ht];
  float4 b4 = *(const float4*)(bias + (tid << 2));
  short4 o4;
  o4.x = f2bf_rne(fmaxf(acc.x * inv + b4.x, 0.f));
  o4.y = f2bf_rne(fmaxf(acc.y * inv + b4.y, 0.f));
  o4.z = f2bf_rne(fmaxf(acc.z * inv + b4.z, 0.f));
  o4.w = f2bf_rne(fmaxf(acc.w * inv + b4.w, 0.f));
  *(short4*)(outp + (size_t)n * HH + (tid << 2)) = o4;
}

// ---------------------------------------------------------------------------
// x_rec = part0 + part1 + bias (f32 out), fused csx. grid (4,128).
// by==0 blocks additionally apply the exact rank-1 lo-plane correction:
// csx[c] += sum_k cs_gat[k] * dfL[c][k].
__global__ __launch_bounds__(256) void xrec_sum_kernel(
    const short* __restrict__ part, const float* __restrict__ bias,
    float* __restrict__ xrec, float* __restrict__ csx,
    const float* __restrict__ cs_gat, const short* __restrict__ dfL)
{
  int c = (blockIdx.x * 256 + threadIdx.x) * 2;
  int r0 = blockIdx.y * 16;
  size_t S = (size_t)N_NODES * 2048;
  float2 b = *(const float2*)(bias + c);
  float sx = 0.f, sy = 0.f;
  for (int r = r0; r < r0 + 16; ++r) {
    size_t off = (size_t)r * 2048 + c;
    short2 p0 = *(const short2*)(part + off);
    short2 p1 = *(const short2*)(part + S + off);
    float vx = bf2f(p0.x) + bf2f(p1.x) + b.x;
    float vy = bf2f(p0.y) + bf2f(p1.y) + b.y;
    *(float2*)(xrec + off) = make_float2(vx, vy);
    sx += vx; sy += vy;
  }
  if (blockIdx.y == 0) {
    const short* rw0 = dfL + (size_t)c * 1024;
    const short* rw1 = dfL + (size_t)(c + 1) * 1024;
    float a0 = 0.f, a1 = 0.f;
    for (int k = 0; k < 1024; k += 4) {
      float4 g = *(const float4*)(cs_gat + k);
      short4 w0 = *(const short4*)(rw0 + k);
      short4 w1 = *(const short4*)(rw1 + k);
      a0 += g.x * bf2f(w0.x) + g.y * bf2f(w0.y) + g.z * bf2f(w0.z) + g.w * bf2f(w0.w);
      a1 += g.x * bf2f(w1.x) + g.y * bf2f(w1.y) + g.z * bf2f(w1.z) + g.w * bf2f(w1.w);
    }
    sx += a0; sy += a1;
  }
  atomicAdd(&csx[c], sx);
  atomicAdd(&csx[c + 1], sy);
}

// ---------------------------------------------------------------------------
__global__ __launch_bounds__(256) void final_kernel(
    const float* __restrict__ Ad, const float* __restrict__ Ai,
    const float* __restrict__ gum, const float* __restrict__ csx,
    const float* __restrict__ csz, float* __restrict__ ce_out,
    float* __restrict__ adj_out)
{
  int i = blockIdx.x;
  int tid = threadIdx.x;
  size_t rb = (size_t)i * 2048;

  float vmax = -INFINITY; int vidx = 0;
  for (int j4 = tid; j4 < 512; j4 += 256) {
    float4 ad = *(const float4*)(Ad  + rb + (size_t)j4 * 4);
    float4 ai = *(const float4*)(Ai  + rb + (size_t)j4 * 4);
    float4 g  = *(const float4*)(gum + rb + (size_t)j4 * 4);
    float4 cx = *(const float4*)(csx + (size_t)j4 * 4);
    float4 cz = *(const float4*)(csz + (size_t)j4 * 4);
    float4 ce;
    ce.x = ad.x * cx.x + ai.x * cz.x;
    ce.y = ad.y * cx.y + ai.y * cz.y;
    ce.z = ad.z * cx.z + ai.z * cz.z;
    ce.w = ad.w * cx.w + ai.w * cz.w;
    *(float4*)(ce_out + rb + (size_t)j4 * 4) = ce;
    int j = j4 * 4;
    float l;
    l = (ce.x + g.x) * 2.0f; if (l > vmax) { vmax = l; vidx = j; }
    l = (ce.y + g.y) * 2.0f; if (l > vmax) { vmax = l; vidx = j + 1; }
    l = (ce.z + g.z) * 2.0f; if (l > vmax) { vmax = l; vidx = j + 2; }
    l = (ce.w + g.w) * 2.0f; if (l > vmax) { vmax = l; vidx = j + 3; }
  }
  for (int m = 1; m < 64; m <<= 1) {
    float ov = __shfl_xor(vmax, m);
    int   oi = __shfl_xor(vidx, m);
    if (ov > vmax || (ov == vmax && oi < vidx)) { vmax = ov; vidx = oi; }
  }
  __shared__ float wm[4];
  __shared__ int   wi[4];
  __shared__ int   amax;
  int lane = tid & 63, wave = tid >> 6;
  if (lane == 0) { wm[wave] = vmax; wi[wave] = vidx; }
  __syncthreads();
  if (tid == 0) {
    float bv = wm[0]; int bi = wi[0];
    for (int w = 1; w < 4; ++w)
      if (wm[w] > bv || (wm[w] == bv && wi[w] < bi)) { bv = wm[w]; bi = wi[w]; }
    amax = bi;
  }
  __syncthreads();
  int am = amax;
  for (int j4 = tid; j4 < 512; j4 += 256) {
    int j = j4 * 4;
    float4 o;
    o.x = (j     == am) ? 1.f : 0.f;
    o.y = (j + 1 == am) ? 1.f : 0.f;
    o.z = (j + 2 == am) ? 1.f : 0.f;
    o.w = (j + 3 == am) ? 1.f : 0.f;
    *(float4*)(adj_out + rb + (size_t)j4 * 4) = o;
  }
}

// ---------------------------------------------------------------------------
extern "C" void kernel_launch(void* const* d_in, const int* in_sizes, int n_in,
                              void* d_out, int out_size, void* d_ws, size_t ws_size,
                              hipStream_t stream) {
  (void)in_sizes; (void)n_in; (void)out_size; (void)ws_size;

  const int*   edge_index = (const int*)d_in[4];   // [2, E]
  const float* lagged     = (const float*)d_in[5];
  const float* eps        = (const float*)d_in[6];
  const float* gumbel     = (const float*)d_in[7];
  const float* enc_Wv     = (const float*)d_in[22];
  const float* enc_bv     = (const float*)d_in[23];
  const float* enc_fc_W   = (const float*)d_in[24];
  const float* enc_fc_b   = (const float*)d_in[25];
  const float* dec_Wv     = (const float*)d_in[30];
  const float* dec_bv     = (const float*)d_in[31];
  const float* gat_Wl     = (const float*)d_in[32];
  const float* gat_bl     = (const float*)d_in[33];
  const float* gat_Wr     = (const float*)d_in[34];
  const float* gat_br     = (const float*)d_in[35];
  const float* gat_att    = (const float*)d_in[36];
  const float* gat_bias   = (const float*)d_in[37];
  const float* dec_fc_W   = (const float*)d_in[38];
  const float* dec_fc_b   = (const float*)d_in[39];
  const float* A_dir      = (const float*)d_in[40];
  const float* A_ind      = (const float*)d_in[41];

  float* out      = (float*)d_out;
  float* out_z    = out;
  float* out_mean = out + (size_t)NL;
  float* out_lv   = out + 2 * (size_t)NL;
  float* out_xrec = out + 3 * (size_t)NL;
  float* out_ce   = out + 4 * (size_t)NL;
  float* out_adj  = out + 5 * (size_t)NL;

  char* ws = (char*)d_ws;
  short* lw_bf = (short*)(ws);                                    //  8 MB
  short* WvH0  = (short*)(ws + ((size_t) 8 << 20));
  short* WvH1  = (short*)(ws + ((size_t)10 << 20));
  short* fcH   = (short*)(ws + ((size_t)12 << 20));               //  2 MB
  short* fcL   = (short*)(ws + ((size_t)14 << 20));
  short* WlH   = (short*)(ws + ((size_t)16 << 20));               // .5 MB
  short* WlL   = (short*)(ws + ((size_t)16 << 20) + (512u << 10));
  short* WrH   = (short*)(ws + ((size_t)17 << 20));
  short* WrL   = (short*)(ws + ((size_t)17 << 20) + (512u << 10));
  short* dfH   = (short*)(ws + ((size_t)18 << 20));               //  4 MB
  short* dfL   = (short*)(ws + ((size_t)22 << 20));
  short* xe_bf = (short*)(ws + ((size_t)26 << 20));               //  1 MB
  short* xd_bf = (short*)(ws + ((size_t)27 << 20));
  short* xl    = (short*)(ws + ((size_t)28 << 20));               //  4 MB
  short* xr    = (short*)(ws + ((size_t)32 << 20));               //  4 MB
  short* gt_bf = (short*)(ws + ((size_t)44 << 20));               //  4 MB
  short* part  = (short*)(ws + ((size_t)48 << 20));               // 16 MB
  int*   cursor = (int*) (ws + ((size_t)64 << 20));               //  8 KB
  int*   csr    = (int*) (ws + ((size_t)64 << 20) + (64u << 10)); //  1 MB
  float* csx    = (float*)(ws + ((size_t)66 << 20));
  float* csz    = (float*)(ws + ((size_t)66 << 20) + (16u << 10));
  float* cs_gat = (float*)(ws + ((size_t)66 << 20) + (32u << 10));

  const int* e_src = edge_index;
  const int* e_dst = edge_index + NE;

  // Mega-A: lw || encWv/decWv H-plane split || init (cursor/csx/csz/cs_gat)
  {
    WCfg2 c2;
    c2.c[0] = { enc_Wv, WvH0, nullptr, 2048, 256, 512 };
    c2.c[1] = { dec_Wv, WvH1, nullptr, 2048, 256, 512 };
    megaA_kernel<<<3080, 256, 0, stream>>>(lagged, lw_bf, c2,
                                           cursor, csx, csz, cs_gat);
  }

  // Mega-C: encV/decV GEMM || remaining weight splits || bucket-CSR fill
  {
    WCfg4 c4;
    c4.c[0] = { enc_fc_W, fcH, fcL, 256,  4096, 1024 };
    c4.c[1] = { gat_Wl,   WlH, WlL, 256,  1024, 256  };
    c4.c[2] = { gat_Wr,   WrH, WrL, 256,  1024, 256  };
    c4.c[3] = { dec_fc_W, dfH, dfL, 1024, 2048, 2048 };
    megaC_kernel<<<4360, 256, 0, stream>>>(
        lw_bf, WvH0, WvH1, part, c4, e_src, e_dst, cursor, csr);
  }

  // split-K reduce -> x_enc/x_dec (bf16)
  sumrelu_kernel<<<512, 256, 0, stream>>>(part, enc_bv, dec_bv, xe_bf, xd_bf);

  // merged: q_params GEMM (mean/lv) + xl/xr twin GEMM in one dispatch
  gemm_dual<<<768, 256, 0, stream>>>(
      xe_bf, xd_bf, fcH, fcL, WlH, WlL, WrH, WrL,
      enc_fc_b, gat_bl, gat_br, out_mean, out_lv, xl, xr);

  // Mega-B: GATv2 || zsum (z + csz)
  megaB_kernel<<<2560, 256, 0, stream>>>(
      xl, xr, gat_att, gat_bias, csr, cursor, gt_bf,
      out_mean, out_lv, eps, out_z, csz);

  // x_rec GEMM: hi-plane only, split-K x2; bn==0 blocks also colsum gt_bf
  // into cs_gat (16-way contention) for the exact rank-1 csx correction
  gemm_xrec<<<dim3(16, 16, 2), 256, 0, stream>>>(gt_bf, dfH, part, cs_gat);
  xrec_sum_kernel<<<dim3(4, 128), 256, 0, stream>>>(
      part, dec_fc_b, out_xrec, csx, cs_gat, dfL);

  // causal effect + hard gumbel one-hot
  final_kernel<<<N_NODES, 256, 0, stream>>>(A_dir, A_ind, gumbel, csx, csz,
                                            out_ce, out_adj);
}

// Round 13
// 188.513 us; speedup vs baseline: 2.0428x; 1.1556x over previous
//
#include <hip/hip_runtime.h>
#include <hip/hip_bf16.h>
#include <math.h>

#define N_NODES 2048
#define DIN     2048
#define HH      1024
#define LAGS    12
#define NE      65536
#define NL      (2048 * 2048)
#define CHUNK   128

#define BM 128
#define BN 128
#define BK 32

typedef __attribute__((ext_vector_type(8))) short short8;
typedef __attribute__((ext_vector_type(4))) float f32x4;

static __device__ __forceinline__ short f2bf_rne(float x) {
  union { float f; unsigned u; } c; c.f = x;
  unsigned u = c.u;
  unsigned r = (u + 0x7fffu + ((u >> 16) & 1u)) >> 16;
  return (short)r;
}
static __device__ __forceinline__ float bf2f(short h) {
  union { unsigned u; float f; } c; c.u = ((unsigned)(unsigned short)h) << 16;
  return c.f;
}

typedef __attribute__((address_space(3))) unsigned int as3_u32;
typedef const __attribute__((address_space(1))) unsigned int as1_u32c;
static __device__ __forceinline__ void gload_lds16(const void* g, void* l) {
  __builtin_amdgcn_global_load_lds((as1_u32c*)g, (as3_u32*)l, 16, 0, 0);
}

// vmcnt is PER-WAVE: each wave issues CPW global_load_lds per stage(); in
// steady state 2*CPW are outstanding; waiting for the previous tile = CPW.
#define VMCNT6  asm volatile("s_waitcnt vmcnt(6)" ::: "memory")
#define VMCNT4  asm volatile("s_waitcnt vmcnt(4)" ::: "memory")
#define VMCNT0  asm volatile("s_waitcnt vmcnt(0)" ::: "memory")
#define SBAR()  do { asm volatile("" ::: "memory"); __builtin_amdgcn_s_barrier(); \
                     asm volatile("" ::: "memory"); } while (0)

struct WCfg { const float* W; short* H; short* L; int K; int N; int nb; };
struct WCfg2 { WCfg c[2]; };
struct WCfg4 { WCfg c[4]; };

// weight transpose + hi/lo split of one 32x32 tile (L optional)
static __device__ __forceinline__ void wsplit_tile(
    const WCfg& cf, int local, int tid, float t[32][33])
{
  const float* W = cf.W;
  short* H = cf.H;
  short* L = cf.L;
  int K = cf.K, N = cf.N;
  int nbx = N >> 5;
  int bx = local % nbx, by = local / nbx;
  int tx = tid & 31, ty = tid >> 5;
  int c0 = bx << 5, k0 = by << 5;
#pragma unroll
  for (int j = 0; j < 4; ++j)
    t[ty + 8 * j][tx] = W[(size_t)(k0 + ty + 8 * j) * N + c0 + tx];
  __syncthreads();
#pragma unroll
  for (int j = 0; j < 4; ++j) {
    int c = ty + 8 * j;
    float x = t[tx][c];
    short h = f2bf_rne(x);
    size_t off = (size_t)(c0 + c) * K + k0 + tx;
    H[off] = h;
    if (L) L[off] = f2bf_rne(x - bf2f(h));
  }
}

// ---------------------------------------------------------------------------
// Mega-A: lw (2048) || encWv/decWv H-plane split (1024) || init (8).
__global__ __launch_bounds__(256) void megaA_kernel(
    const float* __restrict__ lagged, short* __restrict__ lw, WCfg2 cfgs,
    int* __restrict__ cursor, float* __restrict__ csx,
    float* __restrict__ csz, float* __restrict__ cs_gat)
{
  __shared__ float t[32][33];
  int bid = blockIdx.x;
  int tid = threadIdx.x;

  if (bid < 2048) {
    int idx = bid * 256 + tid;
    int n = idx >> 8, c8 = idx & 255;
    const float* base = lagged + (size_t)n * (LAGS * DIN) + (size_t)c8 * 8;
    float a[8] = {};
#pragma unroll
    for (int l = 0; l < LAGS; ++l) {
      float w = (float)((double)(LAGS - l) / 78.0);
      float4 v0 = *(const float4*)(base + (size_t)l * DIN);
      float4 v1 = *(const float4*)(base + (size_t)l * DIN + 4);
      a[0] += w * v0.x; a[1] += w * v0.y; a[2] += w * v0.z; a[3] += w * v0.w;
      a[4] += w * v1.x; a[5] += w * v1.y; a[6] += w * v1.z; a[7] += w * v1.w;
    }
    short8 h;
#pragma unroll
    for (int j = 0; j < 8; ++j) h[j] = f2bf_rne(a[j]);
    *(short8*)(lw + (size_t)idx * 8) = h;
  } else if (bid < 3072) {
    int wb = bid - 2048;
    int i = (wb >= cfgs.c[0].nb) ? 1 : 0;
    int local = wb - (i ? cfgs.c[0].nb : 0);
    wsplit_tile(cfgs.c[i], local, tid, t);
  } else {
    int i = (bid - 3072) * 256 + tid;   // 8 blocks -> 2048
    cursor[i] = 0; csx[i] = 0.f; csz[i] = 0.f;
    if (i < 1024) cs_gat[i] = 0.f;
  }
}

// ---------------------------------------------------------------------------
// Mega-C: encV/decV GEMM (512 blocks, single-plane B, split-K x8) ||
// fc/Wl/Wr/dec_fc weight splits (3584) || bucket-CSR fill (264).
__global__ __launch_bounds__(256) void megaC_kernel(
    const short* __restrict__ A, const short* __restrict__ Bh0,
    const short* __restrict__ Bh1, short* __restrict__ Cpart,
    WCfg4 cfgs,
    const int* __restrict__ esrc, const int* __restrict__ edst,
    int* __restrict__ cursor, int* __restrict__ csr)
{
  __shared__ char smem[32768];
  int fb = blockIdx.x;
  int tid = threadIdx.x;

  if (fb < 512) {
    // ---- gemm (2-plane): M=2048 N=256 K=2048, klen=256, ntwin=2 ----
    short* lds = (short*)smem;
    const int K = 2048, N = 256, M = 2048, klen = 256;
    int lane = tid & 63, wid = tid >> 6;
    int bn = (fb & 1) * BN;
    int bm = ((fb >> 1) & 15) * BM;
    int z = fb >> 5;
    int twin = z & 1;
    int kb = (z >> 1) * klen;
    const short* Bh = twin ? Bh1 : Bh0;

    const short* gp[4];
    int lofs[4];
    {
      int r4 = lane >> 2;
      int ksw = (lane & 3) ^ ((lane >> 3) & 3);
#pragma unroll
      for (int c = 0; c < 4; ++c) {
        int chunk = wid * 4 + c;
        int p = chunk >> 3, s = chunk & 7;
        int r = (s << 4) + r4;
        const short* bp = (p == 0) ? (A + (size_t)(bm + r) * K)
                                   : (Bh + (size_t)(bn + r) * K);
        gp[c] = bp + kb + (ksw << 3);
        lofs[c] = (p << 12) + (s << 9);
      }
    }
    auto stage = [&](int bo) {
#pragma unroll
      for (int c = 0; c < 4; ++c) {
        gload_lds16(gp[c], lds + bo + lofs[c]);
        gp[c] += BK;
      }
    };

    int l15 = lane & 15, l4 = lane >> 4;
    int wr = wid >> 1, wc = wid & 1;
    int soff = (l4 ^ ((l15 >> 1) & 3)) << 3;
    int aoff[4], bhoff[4];
#pragma unroll
    for (int i = 0; i < 4; ++i) {
      int r = wr * 64 + i * 16 + l15;
      int c = wc * 64 + i * 16 + l15;
      aoff[i]  = r * BK + soff;
      bhoff[i] = 4096 + c * BK + soff;
    }

    f32x4 acc[4][4];
#pragma unroll
    for (int m = 0; m < 4; ++m)
#pragma unroll
      for (int n = 0; n < 4; ++n) acc[m][n] = (f32x4){0.f, 0.f, 0.f, 0.f};

    stage(0);
    int cur = 0;
#pragma unroll
    for (int t = 0; t < 8; ++t) {
      if (t + 1 < 8) { stage(cur ? 0 : 8192); VMCNT4; }
      else { VMCNT0; }
      SBAR();
      const short* rb = lds + (cur ? 8192 : 0);
      short8 af[4], bh8[4];
#pragma unroll
      for (int i = 0; i < 4; ++i) {
        af[i]  = *(const short8*)(rb + aoff[i]);
        bh8[i] = *(const short8*)(rb + bhoff[i]);
      }
#pragma unroll
      for (int m = 0; m < 4; ++m)
#pragma unroll
        for (int n = 0; n < 4; ++n)
          acc[m][n] = __builtin_amdgcn_mfma_f32_16x16x32_bf16(af[m], bh8[n], acc[m][n], 0, 0, 0);
      SBAR();
      cur ^= 1;
    }

    short* P = Cpart + (size_t)z * ((size_t)M * N);
#pragma unroll
    for (int n = 0; n < 4; ++n) {
      int col = bn + wc * 64 + n * 16 + l15;
#pragma unroll
      for (int m = 0; m < 4; ++m) {
        int row0 = bm + wr * 64 + m * 16 + (l4 << 2);
#pragma unroll
        for (int r = 0; r < 4; ++r)
          P[(size_t)(row0 + r) * N + col] = f2bf_rne(acc[m][n][r]);
      }
    }
  } else if (fb < 4096) {
    // ---- weight transpose + hi/lo split (fc, Wl, Wr, dec_fc) ----
    float (*t)[33] = (float(*)[33])smem;
    int wb = fb - 512;
    int i = 0, base = 0;
    while (i < 3 && wb >= base + cfgs.c[i].nb) { base += cfgs.c[i].nb; ++i; }
    wsplit_tile(cfgs.c[i], wb - base, tid, t);
  } else {
    // ---- bucket-CSR fill: 128 slots/node; max in-degree ~52 << 128 ----
    int i = (fb - 4096) * 256 + tid;
    if (i < NE) {
      int d = edst[i];
      int p = atomicAdd(&cursor[d], 1);
      if (p < 128) csr[(d << 7) + p] = esrc[i];
    } else if (i < NE + N_NODES) {
      int nn = i - NE;
      int p = atomicAdd(&cursor[nn], 1);
      if (p < 128) csr[(nn << 7) + p] = nn;   // self-loop
    }
  }
}

// ---------------------------------------------------------------------------
// x_rec GEMM: single-plane B (hi only), split-K x2 -> bf16 partials.
// bn==0 blocks additionally colsum their [128 rows x 512 k] patch of A
// (gt_bf) into cs_gat — 16-way atomic contention max — for the exact
// rank-1 lo-plane csx correction in xrec_sum.
// M=2048, N=2048, K=1024, klen=512. grid (16,16,2).
__global__ __launch_bounds__(256) void gemm_xrec(
    const short* __restrict__ A, const short* __restrict__ Bh,
    short* __restrict__ Cpart, float* __restrict__ cs_gat)
{
  __shared__ short lds[2 * 8192];
  const int K = 1024, N = 2048, M = 2048, klen = 512;
  int tid = threadIdx.x;
  int lane = tid & 63, wid = tid >> 6;
  int bn = blockIdx.x * BN, bm = blockIdx.y * BM;
  int z = blockIdx.z;
  int kb = z * klen;

  const short* gp[4];
  int lofs[4];
  {
    int r4 = lane >> 2;
    int ksw = (lane & 3) ^ ((lane >> 3) & 3);
#pragma unroll
    for (int c = 0; c < 4; ++c) {
      int chunk = wid * 4 + c;
      int p = chunk >> 3, s = chunk & 7;
      int r = (s << 4) + r4;
      const short* bp = (p == 0) ? (A + (size_t)(bm + r) * K)
                                 : (Bh + (size_t)(bn + r) * K);
      gp[c] = bp + kb + (ksw << 3);
      lofs[c] = (p << 12) + (s << 9);
    }
  }
  auto stage = [&](int bo) {
#pragma unroll
    for (int c = 0; c < 4; ++c) {
      gload_lds16(gp[c], lds + bo + lofs[c]);
      gp[c] += BK;
    }
  };

  int l15 = lane & 15, l4 = lane >> 4;
  int wr = wid >> 1, wc = wid & 1;
  int soff = (l4 ^ ((l15 >> 1) & 3)) << 3;
  int aoff[4], bhoff[4];
#pragma unroll
  for (int i = 0; i < 4; ++i) {
    int r = wr * 64 + i * 16 + l15;
    int c = wc * 64 + i * 16 + l15;
    aoff[i]  = r * BK + soff;
    bhoff[i] = 4096 + c * BK + soff;
  }

  f32x4 acc[4][4];
#pragma unroll
  for (int m = 0; m < 4; ++m)
#pragma unroll
    for (int n = 0; n < 4; ++n) acc[m][n] = (f32x4){0.f, 0.f, 0.f, 0.f};

  const int nt = klen / BK;   // 16
  stage(0);
  int cur = 0;
  for (int t = 0; t < nt; ++t) {
    if (t + 1 < nt) { stage(cur ? 0 : 8192); VMCNT4; }
    else { VMCNT0; }
    SBAR();
    const short* rb = lds + (cur ? 8192 : 0);
    short8 af[4], bh8[4];
#pragma unroll
    for (int i = 0; i < 4; ++i) {
      af[i]  = *(const short8*)(rb + aoff[i]);
      bh8[i] = *(const short8*)(rb + bhoff[i]);
    }
#pragma unroll
    for (int m = 0; m < 4; ++m)
#pragma unroll
      for (int n = 0; n < 4; ++n)
        acc[m][n] = __builtin_amdgcn_mfma_f32_16x16x32_bf16(af[m], bh8[n], acc[m][n], 0, 0, 0);
    SBAR();
    cur ^= 1;
  }

  short* P = Cpart + (size_t)z * ((size_t)M * N);
#pragma unroll
  for (int n = 0; n < 4; ++n) {
    int col = bn + wc * 64 + n * 16 + l15;
#pragma unroll
    for (int m = 0; m < 4; ++m) {
      int row0 = bm + wr * 64 + m * 16 + (l4 << 2);
#pragma unroll
      for (int r = 0; r < 4; ++r)
        P[(size_t)(row0 + r) * N + col] = f2bf_rne(acc[m][n][r]);
    }
  }

  // cs_gat colsum epilogue (bn==0 blocks tile rows x K exactly once):
  // thread sums 2 k-columns over this block's 128 rows (gt_bf is L2-hot).
  if (blockIdx.x == 0) {
    int k0 = kb + tid * 2;
    float s0 = 0.f, s1 = 0.f;
    const short* Ar = A + (size_t)bm * K + k0;
    for (int r = 0; r < 128; ++r) {
      short2 v = *(const short2*)(Ar + (size_t)r * K);
      s0 += bf2f(v.x);
      s1 += bf2f(v.y);
    }
    atomicAdd(&cs_gat[k0], s0);
    atomicAdd(&cs_gat[k0 + 1], s1);
  }
}

// ---------------------------------------------------------------------------
// Merged GEMM2+GEMM3 (both K=256, nt=8): fb<512: q_params -> f32 mean/lv;
// fb>=512: xl/xr -> bf16. Hi/lo B kept (positive-mean A => coherent colsum).
__global__ __launch_bounds__(256) void gemm_dual(
    const short* __restrict__ xe, const short* __restrict__ xd,
    const short* __restrict__ fcH, const short* __restrict__ fcL,
    const short* __restrict__ WlH, const short* __restrict__ WlL,
    const short* __restrict__ WrH, const short* __restrict__ WrL,
    const float* __restrict__ fc_b, const float* __restrict__ bl,
    const float* __restrict__ br,
    float* __restrict__ out_mean, float* __restrict__ out_lv,
    short* __restrict__ xl, short* __restrict__ xr)
{
  __shared__ short lds[2 * 12288];
  const int K = 256;
  int fb = blockIdx.x;
  const short *A, *Bh, *Bl;
  const float* bias;
  int bm, bn, jobB, ldc;
  short* Obf = nullptr;
  float* Of = nullptr;
  if (fb < 512) {
    A = xe; Bh = fcH; Bl = fcL; bias = fc_b;
    bn = (fb & 31) << 7; bm = (fb >> 5) << 7;
    jobB = 0; ldc = 2048; Of = out_mean;
  } else {
    int g = fb - 512, twin = g & 1, t = g >> 1;
    A = xd; Bh = twin ? WrH : WlH; Bl = twin ? WrL : WlL;
    bias = twin ? br : bl;
    bn = (t & 7) << 7; bm = (t >> 3) << 7;
    jobB = 1; ldc = 1024; Obf = twin ? xr : xl;
  }

  int tid = threadIdx.x;
  int lane = tid & 63, wid = tid >> 6;

  const short* gp[6];
  int lofs[6];
  {
    int r4 = lane >> 2;
    int ksw = (lane & 3) ^ ((lane >> 3) & 3);
#pragma unroll
    for (int c = 0; c < 6; ++c) {
      int chunk = wid * 6 + c;
      int p = chunk >> 3, s = chunk & 7;
      int r = (s << 4) + r4;
      const short* bp = (p == 0) ? (A + (size_t)(bm + r) * K)
                      : (p == 1) ? (Bh + (size_t)(bn + r) * K)
                                 : (Bl + (size_t)(bn + r) * K);
      gp[c] = bp + (ksw << 3);
      lofs[c] = (p << 12) + (s << 9);
    }
  }
  auto stage = [&](int bo) {
#pragma unroll
    for (int c = 0; c < 6; ++c) {
      gload_lds16(gp[c], lds + bo + lofs[c]);
      gp[c] += BK;
    }
  };

  int l15 = lane & 15, l4 = lane >> 4;
  int wr = wid >> 1, wc = wid & 1;
  int soff = (l4 ^ ((l15 >> 1) & 3)) << 3;
  int aoff[4], bhoff[4], bloff[4];
#pragma unroll
  for (int i = 0; i < 4; ++i) {
    int r = wr * 64 + i * 16 + l15;
    int c = wc * 64 + i * 16 + l15;
    aoff[i]  = r * BK + soff;
    bhoff[i] = 4096 + c * BK + soff;
    bloff[i] = 8192 + c * BK + soff;
  }

  f32x4 acc[4][4];
#pragma unroll
  for (int m = 0; m < 4; ++m)
#pragma unroll
    for (int n = 0; n < 4; ++n) acc[m][n] = (f32x4){0.f, 0.f, 0.f, 0.f};

  stage(0);
  int cur = 0;
#pragma unroll
  for (int t = 0; t < 8; ++t) {
    if (t + 1 < 8) { stage(cur ? 0 : 12288); VMCNT6; }
    else { VMCNT0; }
    SBAR();
    const short* rb = lds + (cur ? 12288 : 0);
    short8 af[4], bh8[4], bl8[4];
#pragma unroll
    for (int i = 0; i < 4; ++i) {
      af[i]  = *(const short8*)(rb + aoff[i]);
      bh8[i] = *(const short8*)(rb + bhoff[i]);
      bl8[i] = *(const short8*)(rb + bloff[i]);
    }
#pragma unroll
    for (int m = 0; m < 4; ++m)
#pragma unroll
      for (int n = 0; n < 4; ++n) {
        acc[m][n] = __builtin_amdgcn_mfma_f32_16x16x32_bf16(af[m], bh8[n], acc[m][n], 0, 0, 0);
        acc[m][n] = __builtin_amdgcn_mfma_f32_16x16x32_bf16(af[m], bl8[n], acc[m][n], 0, 0, 0);
      }
    SBAR();
    cur ^= 1;
  }

#pragma unroll
  for (int n = 0; n < 4; ++n) {
    int col = bn + wc * 64 + n * 16 + l15;
    float bv = bias[col];
    if (jobB) {
#pragma unroll
      for (int m = 0; m < 4; ++m) {
        int row0 = bm + wr * 64 + m * 16 + (l4 << 2);
#pragma unroll
        for (int r = 0; r < 4; ++r)
          Obf[(size_t)(row0 + r) * ldc + col] = f2bf_rne(acc[m][n][r] + bv);
      }
    } else {
      float* O = Of; int oc = col;
      if (col >= 2048) { O = out_lv; oc = col - 2048; }
#pragma unroll
      for (int m = 0; m < 4; ++m) {
        int row0 = bm + wr * 64 + m * 16 + (l4 << 2);
#pragma unroll
        for (int r = 0; r < 4; ++r)
          O[(size_t)(row0 + r) * ldc + oc] = acc[m][n][r] + bv;
      }
    }
  }
}

// ---------------------------------------------------------------------------
// split-K reduce (16 bf16 slices) + bias + relu -> bf16 planes x_enc / x_dec
__global__ __launch_bounds__(256) void sumrelu_kernel(
    const short* __restrict__ part, const float* __restrict__ b0,
    const float* __restrict__ b1, short* __restrict__ xe,
    short* __restrict__ xd)
{
  int i4 = blockIdx.x * 256 + threadIdx.x;
  size_t S = (size_t)N_NODES * 256;
  size_t base = (size_t)i4 * 4;
  int col = (int)(base & 255);
  float4 b0v = *(const float4*)(b0 + col);
  float4 b1v = *(const float4*)(b1 + col);
  float s0[4] = {}, s1[4] = {};
#pragma unroll
  for (int c = 0; c < 8; ++c) {
    short4 p0 = *(const short4*)(part + (size_t)(2 * c) * S + base);
    short4 p1 = *(const short4*)(part + (size_t)(2 * c + 1) * S + base);
    s0[0] += bf2f(p0.x); s0[1] += bf2f(p0.y); s0[2] += bf2f(p0.z); s0[3] += bf2f(p0.w);
    s1[0] += bf2f(p1.x); s1[1] += bf2f(p1.y); s1[2] += bf2f(p1.z); s1[3] += bf2f(p1.w);
  }
  short4 e, d;
  e.x = f2bf_rne(fmaxf(s0[0] + b0v.x, 0.f));
  e.y = f2bf_rne(fmaxf(s0[1] + b0v.y, 0.f));
  e.z = f2bf_rne(fmaxf(s0[2] + b0v.z, 0.f));
  e.w = f2bf_rne(fmaxf(s0[3] + b0v.w, 0.f));
  d.x = f2bf_rne(fmaxf(s1[0] + b1v.x, 0.f));
  d.y = f2bf_rne(fmaxf(s1[1] + b1v.y, 0.f));
  d.z = f2bf_rne(fmaxf(s1[2] + b1v.z, 0.f));
  d.w = f2bf_rne(fmaxf(s1[3] + b1v.w, 0.f));
  *(short4*)(xe + base) = e;
  *(short4*)(xd + base) = d;
}

// ---------------------------------------------------------------------------
// Mega-B: GATv2 (2048 blocks, bucket-CSR) || zsum (512 blocks).
__global__ __launch_bounds__(256) void megaB_kernel(
    const short* __restrict__ xl, const short* __restrict__ xr,
    const float* __restrict__ att, const float* __restrict__ bias,
    const int* __restrict__ csr, const int* __restrict__ cursor,
    short* __restrict__ outp,
    const float* __restrict__ mean_in, const float* __restrict__ lv_in,
    const float* __restrict__ eps, float* __restrict__ z,
    float* __restrict__ csz)
{
  __shared__ float xr_s[HH];
  __shared__ float att_s[HH];
  __shared__ float e_s[8 * CHUNK];
  __shared__ int   src_s[CHUNK];
  __shared__ float m_s[8], s_s[8], f_s[8];

  int tid = threadIdx.x;

  if (blockIdx.x >= 2048) {
    int flat = blockIdx.x - 2048;             // 512 blocks
    int c = ((flat & 3) * 256 + tid) * 2;
    int r0 = (flat >> 2) * 16;
    float sx = 0.f, sy = 0.f;
    for (int r = r0; r < r0 + 16; ++r) {
      size_t off = (size_t)r * 2048 + c;
      float2 m = *(const float2*)(mean_in + off);
      float2 v = *(const float2*)(lv_in + off);
      float2 e = *(const float2*)(eps + off);
      float zx = m.x + expf(0.5f * v.x) * e.x;
      float zy = m.y + expf(0.5f * v.y) * e.y;
      *(float2*)(z + off) = make_float2(zx, zy);
      sx += zx; sy += zy;
    }
    atomicAdd(&csz[c], sx);
    atomicAdd(&csz[c + 1], sy);
    return;
  }

  int n = blockIdx.x;
  {
    short4 x4 = ((const short4*)(xr + (size_t)n * HH))[tid];
    xr_s[tid * 4 + 0] = bf2f(x4.x);
    xr_s[tid * 4 + 1] = bf2f(x4.y);
    xr_s[tid * 4 + 2] = bf2f(x4.z);
    xr_s[tid * 4 + 3] = bf2f(x4.w);
  }
  ((float4*)att_s)[tid] = ((const float4*)att)[tid];
  if (tid < 8) { m_s[tid] = -INFINITY; s_s[tid] = 0.f; }
  __syncthreads();

  int beg = n << 7;
  int cnt_total = min(cursor[n], 128);
  int end = beg + cnt_total;
  int ht = tid >> 5;
  float4 acc = make_float4(0.f, 0.f, 0.f, 0.f);

  for (int c0 = beg; c0 < end; c0 += CHUNK) {
    int cnt = min(CHUNK, end - c0);
    if (tid < cnt) src_s[tid] = csr[c0 + tid];
    __syncthreads();

    int wave = tid >> 6, lane = tid & 63;
    int d0 = lane << 4;
    for (int e = wave; e < cnt; e += 4) {
      const short* xlr = xl + (size_t)src_s[e] * HH + d0;
      short8 a0 = *(const short8*)xlr;
      short8 a1 = *(const short8*)(xlr + 8);
      float sum = 0.f;
#pragma unroll
      for (int j = 0; j < 8; ++j) {
        float t = bf2f(a0[j]) + xr_s[d0 + j];
        t = t > 0.f ? t : 0.2f * t;
        sum += t * att_s[d0 + j];
      }
#pragma unroll
      for (int j = 0; j < 8; ++j) {
        float t = bf2f(a1[j]) + xr_s[d0 + 8 + j];
        t = t > 0.f ? t : 0.2f * t;
        sum += t * att_s[d0 + 8 + j];
      }
      sum += __shfl_xor(sum, 1);
      sum += __shfl_xor(sum, 2);
      sum += __shfl_xor(sum, 4);
      if ((lane & 7) == 0) e_s[(lane >> 3) * CHUNK + e] = sum;
    }
    __syncthreads();

    // wave-parallel online-softmax bookkeeping: 32 threads per head
    {
      int h = tid >> 5, i0 = tid & 31;
      float cm = -INFINITY;
      for (int e = i0; e < cnt; e += 32) cm = fmaxf(cm, e_s[h * CHUNK + e]);
#pragma unroll
      for (int m = 1; m < 32; m <<= 1) cm = fmaxf(cm, __shfl_xor(cm, m));
      float m_old = m_s[h];
      float m_new = fmaxf(m_old, cm);
      float csum = 0.f;
      for (int e = i0; e < cnt; e += 32) {
        float p = expf(e_s[h * CHUNK + e] - m_new);
        e_s[h * CHUNK + e] = p;
        csum += p;
      }
#pragma unroll
      for (int m = 1; m < 32; m <<= 1) csum += __shfl_xor(csum, m);
      if (i0 == 0) {
        float f = expf(m_old - m_new);
        s_s[h] = s_s[h] * f + csum;
        m_s[h] = m_new;
        f_s[h] = f;
      }
    }
    __syncthreads();

    float f = f_s[ht];
    acc.x *= f; acc.y *= f; acc.z *= f; acc.w *= f;
    for (int e = 0; e < cnt; ++e) {
      float p = e_s[ht * CHUNK + e];
      short4 v = *(const short4*)(xl + (size_t)src_s[e] * HH + (tid << 2));
      acc.x += p * bf2f(v.x); acc.y += p * bf2f(v.y);
      acc.z += p * bf2f(v.z); acc.w += p * bf2f(v.w);
    }
    __syncthreads();
  }

  float inv = 1.0f / s_s[ht];
  float4 b4 = *(const float4*)(bias + (tid << 2));
  short4 o4;
  o4.x = f2bf_rne(fmaxf(acc.x * inv + b4.x, 0.f));
  o4.y = f2bf_rne(fmaxf(acc.y * inv + b4.y, 0.f));
  o4.z = f2bf_rne(fmaxf(acc.z * inv + b4.z, 0.f));
  o4.w = f2bf_rne(fmaxf(acc.w * inv + b4.w, 0.f));
  *(short4*)(outp + (size_t)n * HH + (tid << 2)) = o4;
}

// ---------------------------------------------------------------------------
// x_rec = part0 + part1 + bias (f32 out), fused csx. grid (4,128).
// The exact rank-1 lo-plane correction csx[c] += sum_k cs_gat[k]*dfL[c][k]
// is DISTRIBUTED over the 128 by-groups (8 k each) — round-12's by==0-only
// version was a 4-block latency-bound GEMV tail (~20 us).
__global__ __launch_bounds__(256) void xrec_sum_kernel(
    const short* __restrict__ part, const float* __restrict__ bias,
    float* __restrict__ xrec, float* __restrict__ csx,
    const float* __restrict__ cs_gat, const short* __restrict__ dfL)
{
  int c = (blockIdx.x * 256 + threadIdx.x) * 2;
  int r0 = blockIdx.y * 16;
  size_t S = (size_t)N_NODES * 2048;
  float2 b = *(const float2*)(bias + c);
  float sx = 0.f, sy = 0.f;
  for (int r = r0; r < r0 + 16; ++r) {
    size_t off = (size_t)r * 2048 + c;
    short2 p0 = *(const short2*)(part + off);
    short2 p1 = *(const short2*)(part + S + off);
    float vx = bf2f(p0.x) + bf2f(p1.x) + b.x;
    float vy = bf2f(p0.y) + bf2f(p1.y) + b.y;
    *(float2*)(xrec + off) = make_float2(vx, vy);
    sx += vx; sy += vy;
  }
  {
    // this block's 8-k slice of the rank-1 correction
    int k0 = blockIdx.y * 8;
    const short* rw0 = dfL + (size_t)c * 1024 + k0;
    const short* rw1 = dfL + (size_t)(c + 1) * 1024 + k0;
#pragma unroll
    for (int j = 0; j < 8; j += 4) {
      float4 g = *(const float4*)(cs_gat + k0 + j);
      short4 w0 = *(const short4*)(rw0 + j);
      short4 w1 = *(const short4*)(rw1 + j);
      sx += g.x * bf2f(w0.x) + g.y * bf2f(w0.y) + g.z * bf2f(w0.z) + g.w * bf2f(w0.w);
      sy += g.x * bf2f(w1.x) + g.y * bf2f(w1.y) + g.z * bf2f(w1.z) + g.w * bf2f(w1.w);
    }
  }
  atomicAdd(&csx[c], sx);
  atomicAdd(&csx[c + 1], sy);
}

// ---------------------------------------------------------------------------
__global__ __launch_bounds__(256) void final_kernel(
    const float* __restrict__ Ad, const float* __restrict__ Ai,
    const float* __restrict__ gum, const float* __restrict__ csx,
    const float* __restrict__ csz, float* __restrict__ ce_out,
    float* __restrict__ adj_out)
{
  int i = blockIdx.x;
  int tid = threadIdx.x;
  size_t rb = (size_t)i * 2048;

  float vmax = -INFINITY; int vidx = 0;
  for (int j4 = tid; j4 < 512; j4 += 256) {
    float4 ad = *(const float4*)(Ad  + rb + (size_t)j4 * 4);
    float4 ai = *(const float4*)(Ai  + rb + (size_t)j4 * 4);
    float4 g  = *(const float4*)(gum + rb + (size_t)j4 * 4);
    float4 cx = *(const float4*)(csx + (size_t)j4 * 4);
    float4 cz = *(const float4*)(csz + (size_t)j4 * 4);
    float4 ce;
    ce.x = ad.x * cx.x + ai.x * cz.x;
    ce.y = ad.y * cx.y + ai.y * cz.y;
    ce.z = ad.z * cx.z + ai.z * cz.z;
    ce.w = ad.w * cx.w + ai.w * cz.w;
    *(float4*)(ce_out + rb + (size_t)j4 * 4) = ce;
    int j = j4 * 4;
    float l;
    l = (ce.x + g.x) * 2.0f; if (l > vmax) { vmax = l; vidx = j; }
    l = (ce.y + g.y) * 2.0f; if (l > vmax) { vmax = l; vidx = j + 1; }
    l = (ce.z + g.z) * 2.0f; if (l > vmax) { vmax = l; vidx = j + 2; }
    l = (ce.w + g.w) * 2.0f; if (l > vmax) { vmax = l; vidx = j + 3; }
  }
  for (int m = 1; m < 64; m <<= 1) {
    float ov = __shfl_xor(vmax, m);
    int   oi = __shfl_xor(vidx, m);
    if (ov > vmax || (ov == vmax && oi < vidx)) { vmax = ov; vidx = oi; }
  }
  __shared__ float wm[4];
  __shared__ int   wi[4];
  __shared__ int   amax;
  int lane = tid & 63, wave = tid >> 6;
  if (lane == 0) { wm[wave] = vmax; wi[wave] = vidx; }
  __syncthreads();
  if (tid == 0) {
    float bv = wm[0]; int bi = wi[0];
    for (int w = 1; w < 4; ++w)
      if (wm[w] > bv || (wm[w] == bv && wi[w] < bi)) { bv = wm[w]; bi = wi[w]; }
    amax = bi;
  }
  __syncthreads();
  int am = amax;
  for (int j4 = tid; j4 < 512; j4 += 256) {
    int j = j4 * 4;
    float4 o;
    o.x = (j     == am) ? 1.f : 0.f;
    o.y = (j + 1 == am) ? 1.f : 0.f;
    o.z = (j + 2 == am) ? 1.f : 0.f;
    o.w = (j + 3 == am) ? 1.f : 0.f;
    *(float4*)(adj_out + rb + (size_t)j4 * 4) = o;
  }
}

// ---------------------------------------------------------------------------
extern "C" void kernel_launch(void* const* d_in, const int* in_sizes, int n_in,
                              void* d_out, int out_size, void* d_ws, size_t ws_size,
                              hipStream_t stream) {
  (void)in_sizes; (void)n_in; (void)out_size; (void)ws_size;

  const int*   edge_index = (const int*)d_in[4];   // [2, E]
  const float* lagged     = (const float*)d_in[5];
  const float* eps        = (const float*)d_in[6];
  const float* gumbel     = (const float*)d_in[7];
  const float* enc_Wv     = (const float*)d_in[22];
  const float* enc_bv     = (const float*)d_in[23];
  const float* enc_fc_W   = (const float*)d_in[24];
  const float* enc_fc_b   = (const float*)d_in[25];
  const float* dec_Wv     = (const float*)d_in[30];
  const float* dec_bv     = (const float*)d_in[31];
  const float* gat_Wl     = (const float*)d_in[32];
  const float* gat_bl     = (const float*)d_in[33];
  const float* gat_Wr     = (const float*)d_in[34];
  const float* gat_br     = (const float*)d_in[35];
  const float* gat_att    = (const float*)d_in[36];
  const float* gat_bias   = (const float*)d_in[37];
  const float* dec_fc_W   = (const float*)d_in[38];
  const float* dec_fc_b   = (const float*)d_in[39];
  const float* A_dir      = (const float*)d_in[40];
  const float* A_ind      = (const float*)d_in[41];

  float* out      = (float*)d_out;
  float* out_z    = out;
  float* out_mean = out + (size_t)NL;
  float* out_lv   = out + 2 * (size_t)NL;
  float* out_xrec = out + 3 * (size_t)NL;
  float* out_ce   = out + 4 * (size_t)NL;
  float* out_adj  = out + 5 * (size_t)NL;

  char* ws = (char*)d_ws;
  short* lw_bf = (short*)(ws);                                    //  8 MB
  short* WvH0  = (short*)(ws + ((size_t) 8 << 20));
  short* WvH1  = (short*)(ws + ((size_t)10 << 20));
  short* fcH   = (short*)(ws + ((size_t)12 << 20));               //  2 MB
  short* fcL   = (short*)(ws + ((size_t)14 << 20));
  short* WlH   = (short*)(ws + ((size_t)16 << 20));               // .5 MB
  short* WlL   = (short*)(ws + ((size_t)16 << 20) + (512u << 10));
  short* WrH   = (short*)(ws + ((size_t)17 << 20));
  short* WrL   = (short*)(ws + ((size_t)17 << 20) + (512u << 10));
  short* dfH   = (short*)(ws + ((size_t)18 << 20));               //  4 MB
  short* dfL   = (short*)(ws + ((size_t)22 << 20));
  short* xe_bf = (short*)(ws + ((size_t)26 << 20));               //  1 MB
  short* xd_bf = (short*)(ws + ((size_t)27 << 20));
  short* xl    = (short*)(ws + ((size_t)28 << 20));               //  4 MB
  short* xr    = (short*)(ws + ((size_t)32 << 20));               //  4 MB
  short* gt_bf = (short*)(ws + ((size_t)44 << 20));               //  4 MB
  short* part  = (short*)(ws + ((size_t)48 << 20));               // 16 MB
  int*   cursor = (int*) (ws + ((size_t)64 << 20));               //  8 KB
  int*   csr    = (int*) (ws + ((size_t)64 << 20) + (64u << 10)); //  1 MB
  float* csx    = (float*)(ws + ((size_t)66 << 20));
  float* csz    = (float*)(ws + ((size_t)66 << 20) + (16u << 10));
  float* cs_gat = (float*)(ws + ((size_t)66 << 20) + (32u << 10));

  const int* e_src = edge_index;
  const int* e_dst = edge_index + NE;

  // Mega-A: lw || encWv/decWv H-plane split || init (cursor/csx/csz/cs_gat)
  {
    WCfg2 c2;
    c2.c[0] = { enc_Wv, WvH0, nullptr, 2048, 256, 512 };
    c2.c[1] = { dec_Wv, WvH1, nullptr, 2048, 256, 512 };
    megaA_kernel<<<3080, 256, 0, stream>>>(lagged, lw_bf, c2,
                                           cursor, csx, csz, cs_gat);
  }

  // Mega-C: encV/decV GEMM || remaining weight splits || bucket-CSR fill
  {
    WCfg4 c4;
    c4.c[0] = { enc_fc_W, fcH, fcL, 256,  4096, 1024 };
    c4.c[1] = { gat_Wl,   WlH, WlL, 256,  1024, 256  };
    c4.c[2] = { gat_Wr,   WrH, WrL, 256,  1024, 256  };
    c4.c[3] = { dec_fc_W, dfH, dfL, 1024, 2048, 2048 };
    megaC_kernel<<<4360, 256, 0, stream>>>(
        lw_bf, WvH0, WvH1, part, c4, e_src, e_dst, cursor, csr);
  }

  // split-K reduce -> x_enc/x_dec (bf16)
  sumrelu_kernel<<<512, 256, 0, stream>>>(part, enc_bv, dec_bv, xe_bf, xd_bf);

  // merged: q_params GEMM (mean/lv) + xl/xr twin GEMM in one dispatch
  gemm_dual<<<768, 256, 0, stream>>>(
      xe_bf, xd_bf, fcH, fcL, WlH, WlL, WrH, WrL,
      enc_fc_b, gat_bl, gat_br, out_mean, out_lv, xl, xr);

  // Mega-B: GATv2 || zsum (z + csz)
  megaB_kernel<<<2560, 256, 0, stream>>>(
      xl, xr, gat_att, gat_bias, csr, cursor, gt_bf,
      out_mean, out_lv, eps, out_z, csz);

  // x_rec GEMM: hi-plane only, split-K x2; bn==0 blocks also colsum gt_bf
  // into cs_gat (16-way contention) for the exact rank-1 csx correction
  gemm_xrec<<<dim3(16, 16, 2), 256, 0, stream>>>(gt_bf, dfH, part, cs_gat);
  xrec_sum_kernel<<<dim3(4, 128), 256, 0, stream>>>(
      part, dec_fc_b, out_xrec, csx, cs_gat, dfL);

  // causal effect + hard gumbel one-hot
  final_kernel<<<N_NODES, 256, 0, stream>>>(A_dir, A_ind, gumbel, csx, csz,
                                            out_ce, out_adj);
}

// Round 14
// 185.342 us; speedup vs baseline: 2.0777x; 1.0171x over previous
//
#include <hip/hip_runtime.h>
#include <hip/hip_bf16.h>
#include <math.h>

#define N_NODES 2048
#define DIN     2048
#define HH      1024
#define LAGS    12
#define NE      65536
#define NL      (2048 * 2048)
#define CHUNK   128

#define BM 128
#define BN 128
#define BK 32

typedef __attribute__((ext_vector_type(8))) short short8;
typedef __attribute__((ext_vector_type(4))) float f32x4;

static __device__ __forceinline__ short f2bf_rne(float x) {
  union { float f; unsigned u; } c; c.f = x;
  unsigned u = c.u;
  unsigned r = (u + 0x7fffu + ((u >> 16) & 1u)) >> 16;
  return (short)r;
}
static __device__ __forceinline__ float bf2f(short h) {
  union { unsigned u; float f; } c; c.u = ((unsigned)(unsigned short)h) << 16;
  return c.f;
}

typedef __attribute__((address_space(3))) unsigned int as3_u32;
typedef const __attribute__((address_space(1))) unsigned int as1_u32c;
static __device__ __forceinline__ void gload_lds16(const void* g, void* l) {
  __builtin_amdgcn_global_load_lds((as1_u32c*)g, (as3_u32*)l, 16, 0, 0);
}

// vmcnt is PER-WAVE: each wave issues CPW global_load_lds per stage(); in
// steady state 2*CPW are outstanding; waiting for the previous tile = CPW.
#define VMCNT6  asm volatile("s_waitcnt vmcnt(6)" ::: "memory")
#define VMCNT4  asm volatile("s_waitcnt vmcnt(4)" ::: "memory")
#define VMCNT0  asm volatile("s_waitcnt vmcnt(0)" ::: "memory")
#define SBAR()  do { asm volatile("" ::: "memory"); __builtin_amdgcn_s_barrier(); \
                     asm volatile("" ::: "memory"); } while (0)

struct WCfg { const float* W; short* H; short* L; int K; int N; int nb; };
struct WCfg2 { WCfg c[2]; };
struct WCfg4 { WCfg c[4]; };

// weight transpose + hi/lo split of one 32x32 tile (L optional)
static __device__ __forceinline__ void wsplit_tile(
    const WCfg& cf, int local, int tid, float t[32][33])
{
  const float* W = cf.W;
  short* H = cf.H;
  short* L = cf.L;
  int K = cf.K, N = cf.N;
  int nbx = N >> 5;
  int bx = local % nbx, by = local / nbx;
  int tx = tid & 31, ty = tid >> 5;
  int c0 = bx << 5, k0 = by << 5;
#pragma unroll
  for (int j = 0; j < 4; ++j)
    t[ty + 8 * j][tx] = W[(size_t)(k0 + ty + 8 * j) * N + c0 + tx];
  __syncthreads();
#pragma unroll
  for (int j = 0; j < 4; ++j) {
    int c = ty + 8 * j;
    float x = t[tx][c];
    short h = f2bf_rne(x);
    size_t off = (size_t)(c0 + c) * K + k0 + tx;
    H[off] = h;
    if (L) L[off] = f2bf_rne(x - bf2f(h));
  }
}

// ---------------------------------------------------------------------------
// Mega-A: lw (2048) || encWv/decWv H-plane split (1024) || init (8).
__global__ __launch_bounds__(256) void megaA_kernel(
    const float* __restrict__ lagged, short* __restrict__ lw, WCfg2 cfgs,
    int* __restrict__ cursor, float* __restrict__ csx,
    float* __restrict__ csz, float* __restrict__ cs_gat)
{
  __shared__ float t[32][33];
  int bid = blockIdx.x;
  int tid = threadIdx.x;

  if (bid < 2048) {
    int idx = bid * 256 + tid;
    int n = idx >> 8, c8 = idx & 255;
    const float* base = lagged + (size_t)n * (LAGS * DIN) + (size_t)c8 * 8;
    float a[8] = {};
#pragma unroll
    for (int l = 0; l < LAGS; ++l) {
      float w = (float)((double)(LAGS - l) / 78.0);
      float4 v0 = *(const float4*)(base + (size_t)l * DIN);
      float4 v1 = *(const float4*)(base + (size_t)l * DIN + 4);
      a[0] += w * v0.x; a[1] += w * v0.y; a[2] += w * v0.z; a[3] += w * v0.w;
      a[4] += w * v1.x; a[5] += w * v1.y; a[6] += w * v1.z; a[7] += w * v1.w;
    }
    short8 h;
#pragma unroll
    for (int j = 0; j < 8; ++j) h[j] = f2bf_rne(a[j]);
    *(short8*)(lw + (size_t)idx * 8) = h;
  } else if (bid < 3072) {
    int wb = bid - 2048;
    int i = (wb >= cfgs.c[0].nb) ? 1 : 0;
    int local = wb - (i ? cfgs.c[0].nb : 0);
    wsplit_tile(cfgs.c[i], local, tid, t);
  } else {
    int i = (bid - 3072) * 256 + tid;   // 8 blocks -> 2048
    cursor[i] = 0; csx[i] = 0.f; csz[i] = 0.f;
    if (i < 1024) cs_gat[i] = 0.f;
  }
}

// ---------------------------------------------------------------------------
// Mega-C: encV/decV GEMM (256 blocks, single-plane B, split-K x4) ||
// fc/Wl/Wr/dec_fc weight splits (3584) || bucket-CSR fill (264).
__global__ __launch_bounds__(256) void megaC_kernel(
    const short* __restrict__ A, const short* __restrict__ Bh0,
    const short* __restrict__ Bh1, short* __restrict__ Cpart,
    WCfg4 cfgs,
    const int* __restrict__ esrc, const int* __restrict__ edst,
    int* __restrict__ cursor, int* __restrict__ csr)
{
  __shared__ char smem[32768];
  int fb = blockIdx.x;
  int tid = threadIdx.x;

  if (fb < 256) {
    // ---- gemm (2-plane): M=2048 N=256 K=2048, klen=512, ntwin=2 ----
    short* lds = (short*)smem;
    const int K = 2048, N = 256, M = 2048, klen = 512;
    int lane = tid & 63, wid = tid >> 6;
    int bn = (fb & 1) * BN;
    int bm = ((fb >> 1) & 15) * BM;
    int z = fb >> 5;                 // [0,8)
    int twin = z & 1;
    int kb = (z >> 1) * klen;
    const short* Bh = twin ? Bh1 : Bh0;

    const short* gp[4];
    int lofs[4];
    {
      int r4 = lane >> 2;
      int ksw = (lane & 3) ^ ((lane >> 3) & 3);
#pragma unroll
      for (int c = 0; c < 4; ++c) {
        int chunk = wid * 4 + c;
        int p = chunk >> 3, s = chunk & 7;
        int r = (s << 4) + r4;
        const short* bp = (p == 0) ? (A + (size_t)(bm + r) * K)
                                   : (Bh + (size_t)(bn + r) * K);
        gp[c] = bp + kb + (ksw << 3);
        lofs[c] = (p << 12) + (s << 9);
      }
    }
    auto stage = [&](int bo) {
#pragma unroll
      for (int c = 0; c < 4; ++c) {
        gload_lds16(gp[c], lds + bo + lofs[c]);
        gp[c] += BK;
      }
    };

    int l15 = lane & 15, l4 = lane >> 4;
    int wr = wid >> 1, wc = wid & 1;
    int soff = (l4 ^ ((l15 >> 1) & 3)) << 3;
    int aoff[4], bhoff[4];
#pragma unroll
    for (int i = 0; i < 4; ++i) {
      int r = wr * 64 + i * 16 + l15;
      int c = wc * 64 + i * 16 + l15;
      aoff[i]  = r * BK + soff;
      bhoff[i] = 4096 + c * BK + soff;
    }

    f32x4 acc[4][4];
#pragma unroll
    for (int m = 0; m < 4; ++m)
#pragma unroll
      for (int n = 0; n < 4; ++n) acc[m][n] = (f32x4){0.f, 0.f, 0.f, 0.f};

    const int nt = klen / BK;   // 16
    stage(0);
    int cur = 0;
    for (int t = 0; t < nt; ++t) {
      if (t + 1 < nt) { stage(cur ? 0 : 8192); VMCNT4; }
      else { VMCNT0; }
      SBAR();
      const short* rb = lds + (cur ? 8192 : 0);
      short8 af[4], bh8[4];
#pragma unroll
      for (int i = 0; i < 4; ++i) {
        af[i]  = *(const short8*)(rb + aoff[i]);
        bh8[i] = *(const short8*)(rb + bhoff[i]);
      }
#pragma unroll
      for (int m = 0; m < 4; ++m)
#pragma unroll
        for (int n = 0; n < 4; ++n)
          acc[m][n] = __builtin_amdgcn_mfma_f32_16x16x32_bf16(af[m], bh8[n], acc[m][n], 0, 0, 0);
      SBAR();
      cur ^= 1;
    }

    short* P = Cpart + (size_t)z * ((size_t)M * N);
#pragma unroll
    for (int n = 0; n < 4; ++n) {
      int col = bn + wc * 64 + n * 16 + l15;
#pragma unroll
      for (int m = 0; m < 4; ++m) {
        int row0 = bm + wr * 64 + m * 16 + (l4 << 2);
#pragma unroll
        for (int r = 0; r < 4; ++r)
          P[(size_t)(row0 + r) * N + col] = f2bf_rne(acc[m][n][r]);
      }
    }
  } else if (fb < 3840) {
    // ---- weight transpose + hi/lo split (fc, Wl, Wr, dec_fc) ----
    float (*t)[33] = (float(*)[33])smem;
    int wb = fb - 256;
    int i = 0, base = 0;
    while (i < 3 && wb >= base + cfgs.c[i].nb) { base += cfgs.c[i].nb; ++i; }
    wsplit_tile(cfgs.c[i], wb - base, tid, t);
  } else {
    // ---- bucket-CSR fill: 128 slots/node; max in-degree ~52 << 128 ----
    int i = (fb - 3840) * 256 + tid;
    if (i < NE) {
      int d = edst[i];
      int p = atomicAdd(&cursor[d], 1);
      if (p < 128) csr[(d << 7) + p] = esrc[i];
    } else if (i < NE + N_NODES) {
      int nn = i - NE;
      int p = atomicAdd(&cursor[nn], 1);
      if (p < 128) csr[(nn << 7) + p] = nn;   // self-loop
    }
  }
}

// ---------------------------------------------------------------------------
// x_rec GEMM: single-plane B (hi only), split-K x2 -> bf16 partials.
// bn==0 blocks additionally colsum their [128 rows x 512 k] patch of A
// (gt_bf) into cs_gat for the exact rank-1 lo-plane csx correction.
// M=2048, N=2048, K=1024, klen=512. grid (16,16,2).
__global__ __launch_bounds__(256) void gemm_xrec(
    const short* __restrict__ A, const short* __restrict__ Bh,
    short* __restrict__ Cpart, float* __restrict__ cs_gat)
{
  __shared__ short lds[2 * 8192];
  const int K = 1024, N = 2048, M = 2048, klen = 512;
  int tid = threadIdx.x;
  int lane = tid & 63, wid = tid >> 6;
  int bn = blockIdx.x * BN, bm = blockIdx.y * BM;
  int z = blockIdx.z;
  int kb = z * klen;

  const short* gp[4];
  int lofs[4];
  {
    int r4 = lane >> 2;
    int ksw = (lane & 3) ^ ((lane >> 3) & 3);
#pragma unroll
    for (int c = 0; c < 4; ++c) {
      int chunk = wid * 4 + c;
      int p = chunk >> 3, s = chunk & 7;
      int r = (s << 4) + r4;
      const short* bp = (p == 0) ? (A + (size_t)(bm + r) * K)
                                 : (Bh + (size_t)(bn + r) * K);
      gp[c] = bp + kb + (ksw << 3);
      lofs[c] = (p << 12) + (s << 9);
    }
  }
  auto stage = [&](int bo) {
#pragma unroll
    for (int c = 0; c < 4; ++c) {
      gload_lds16(gp[c], lds + bo + lofs[c]);
      gp[c] += BK;
    }
  };

  int l15 = lane & 15, l4 = lane >> 4;
  int wr = wid >> 1, wc = wid & 1;
  int soff = (l4 ^ ((l15 >> 1) & 3)) << 3;
  int aoff[4], bhoff[4];
#pragma unroll
  for (int i = 0; i < 4; ++i) {
    int r = wr * 64 + i * 16 + l15;
    int c = wc * 64 + i * 16 + l15;
    aoff[i]  = r * BK + soff;
    bhoff[i] = 4096 + c * BK + soff;
  }

  f32x4 acc[4][4];
#pragma unroll
  for (int m = 0; m < 4; ++m)
#pragma unroll
    for (int n = 0; n < 4; ++n) acc[m][n] = (f32x4){0.f, 0.f, 0.f, 0.f};

  const int nt = klen / BK;   // 16
  stage(0);
  int cur = 0;
  for (int t = 0; t < nt; ++t) {
    if (t + 1 < nt) { stage(cur ? 0 : 8192); VMCNT4; }
    else { VMCNT0; }
    SBAR();
    const short* rb = lds + (cur ? 8192 : 0);
    short8 af[4], bh8[4];
#pragma unroll
    for (int i = 0; i < 4; ++i) {
      af[i]  = *(const short8*)(rb + aoff[i]);
      bh8[i] = *(const short8*)(rb + bhoff[i]);
    }
#pragma unroll
    for (int m = 0; m < 4; ++m)
#pragma unroll
      for (int n = 0; n < 4; ++n)
        acc[m][n] = __builtin_amdgcn_mfma_f32_16x16x32_bf16(af[m], bh8[n], acc[m][n], 0, 0, 0);
    SBAR();
    cur ^= 1;
  }

  short* P = Cpart + (size_t)z * ((size_t)M * N);
#pragma unroll
  for (int n = 0; n < 4; ++n) {
    int col = bn + wc * 64 + n * 16 + l15;
#pragma unroll
    for (int m = 0; m < 4; ++m) {
      int row0 = bm + wr * 64 + m * 16 + (l4 << 2);
#pragma unroll
      for (int r = 0; r < 4; ++r)
        P[(size_t)(row0 + r) * N + col] = f2bf_rne(acc[m][n][r]);
    }
  }

  if (blockIdx.x == 0) {
    int k0 = kb + tid * 2;
    float s0 = 0.f, s1 = 0.f;
    const short* Ar = A + (size_t)bm * K + k0;
    for (int r = 0; r < 128; ++r) {
      short2 v = *(const short2*)(Ar + (size_t)r * K);
      s0 += bf2f(v.x);
      s1 += bf2f(v.y);
    }
    atomicAdd(&cs_gat[k0], s0);
    atomicAdd(&cs_gat[k0 + 1], s1);
  }
}

// ---------------------------------------------------------------------------
// Merged GEMM2+GEMM3 (both K=256, nt=8).
// fb <  512: q_params = xe @ (fcH+fcL) -> f32 mean/lv (hi/lo kept:
//            positive-mean A => coherent colsum through csz).
// fb >= 512: xl/xr = xd @ WlH/WrH -> bf16 (single-plane: dropped lo term
//            is ~1e-3 relative on xl, attenuates to ~1e-7 on ce — safe).
__global__ __launch_bounds__(256) void gemm_dual(
    const short* __restrict__ xe, const short* __restrict__ xd,
    const short* __restrict__ fcH, const short* __restrict__ fcL,
    const short* __restrict__ WlH, const short* __restrict__ WrH,
    const float* __restrict__ fc_b, const float* __restrict__ bl,
    const float* __restrict__ br,
    float* __restrict__ out_mean, float* __restrict__ out_lv,
    short* __restrict__ xl, short* __restrict__ xr)
{
  __shared__ short lds[2 * 12288];
  const int K = 256;
  int fb = blockIdx.x;
  int tid = threadIdx.x;
  int lane = tid & 63, wid = tid >> 6;
  int l15 = lane & 15, l4 = lane >> 4;
  int wr = wid >> 1, wc = wid & 1;
  int soff = (l4 ^ ((l15 >> 1) & 3)) << 3;

  if (fb < 512) {
    // ---- fc job: 3-plane hi/lo pipeline ----
    const short* A = xe;
    int bn = (fb & 31) << 7, bm = (fb >> 5) << 7;

    const short* gp[6];
    int lofs[6];
    {
      int r4 = lane >> 2;
      int ksw = (lane & 3) ^ ((lane >> 3) & 3);
#pragma unroll
      for (int c = 0; c < 6; ++c) {
        int chunk = wid * 6 + c;
        int p = chunk >> 3, s = chunk & 7;
        int r = (s << 4) + r4;
        const short* bp = (p == 0) ? (A + (size_t)(bm + r) * K)
                        : (p == 1) ? (fcH + (size_t)(bn + r) * K)
                                   : (fcL + (size_t)(bn + r) * K);
        gp[c] = bp + (ksw << 3);
        lofs[c] = (p << 12) + (s << 9);
      }
    }
    auto stage = [&](int bo) {
#pragma unroll
      for (int c = 0; c < 6; ++c) {
        gload_lds16(gp[c], lds + bo + lofs[c]);
        gp[c] += BK;
      }
    };

    int aoff[4], bhoff[4], bloff[4];
#pragma unroll
    for (int i = 0; i < 4; ++i) {
      int r = wr * 64 + i * 16 + l15;
      int c = wc * 64 + i * 16 + l15;
      aoff[i]  = r * BK + soff;
      bhoff[i] = 4096 + c * BK + soff;
      bloff[i] = 8192 + c * BK + soff;
    }

    f32x4 acc[4][4];
#pragma unroll
    for (int m = 0; m < 4; ++m)
#pragma unroll
      for (int n = 0; n < 4; ++n) acc[m][n] = (f32x4){0.f, 0.f, 0.f, 0.f};

    stage(0);
    int cur = 0;
#pragma unroll
    for (int t = 0; t < 8; ++t) {
      if (t + 1 < 8) { stage(cur ? 0 : 12288); VMCNT6; }
      else { VMCNT0; }
      SBAR();
      const short* rb = lds + (cur ? 12288 : 0);
      short8 af[4], bh8[4], bl8[4];
#pragma unroll
      for (int i = 0; i < 4; ++i) {
        af[i]  = *(const short8*)(rb + aoff[i]);
        bh8[i] = *(const short8*)(rb + bhoff[i]);
        bl8[i] = *(const short8*)(rb + bloff[i]);
      }
#pragma unroll
      for (int m = 0; m < 4; ++m)
#pragma unroll
        for (int n = 0; n < 4; ++n) {
          acc[m][n] = __builtin_amdgcn_mfma_f32_16x16x32_bf16(af[m], bh8[n], acc[m][n], 0, 0, 0);
          acc[m][n] = __builtin_amdgcn_mfma_f32_16x16x32_bf16(af[m], bl8[n], acc[m][n], 0, 0, 0);
        }
      SBAR();
      cur ^= 1;
    }

#pragma unroll
    for (int n = 0; n < 4; ++n) {
      int col = bn + wc * 64 + n * 16 + l15;
      float bv = fc_b[col];
      float* O = out_mean; int oc = col;
      if (col >= 2048) { O = out_lv; oc = col - 2048; }
#pragma unroll
      for (int m = 0; m < 4; ++m) {
        int row0 = bm + wr * 64 + m * 16 + (l4 << 2);
#pragma unroll
        for (int r = 0; r < 4; ++r)
          O[(size_t)(row0 + r) * 2048 + oc] = acc[m][n][r] + bv;
      }
    }
  } else {
    // ---- xl/xr job: 2-plane single-product pipeline ----
    int g = fb - 512, twin = g & 1, t0 = g >> 1;
    const short* A = xd;
    const short* Bh = twin ? WrH : WlH;
    const float* bias = twin ? br : bl;
    int bn = (t0 & 7) << 7, bm = (t0 >> 3) << 7;
    short* Obf = twin ? xr : xl;

    const short* gp[4];
    int lofs[4];
    {
      int r4 = lane >> 2;
      int ksw = (lane & 3) ^ ((lane >> 3) & 3);
#pragma unroll
      for (int c = 0; c < 4; ++c) {
        int chunk = wid * 4 + c;
        int p = chunk >> 3, s = chunk & 7;
        int r = (s << 4) + r4;
        const short* bp = (p == 0) ? (A + (size_t)(bm + r) * K)
                                   : (Bh + (size_t)(bn + r) * K);
        gp[c] = bp + (ksw << 3);
        lofs[c] = (p << 12) + (s << 9);
      }
    }
    auto stage = [&](int bo) {
#pragma unroll
      for (int c = 0; c < 4; ++c) {
        gload_lds16(gp[c], lds + bo + lofs[c]);
        gp[c] += BK;
      }
    };

    int aoff[4], bhoff[4];
#pragma unroll
    for (int i = 0; i < 4; ++i) {
      int r = wr * 64 + i * 16 + l15;
      int c = wc * 64 + i * 16 + l15;
      aoff[i]  = r * BK + soff;
      bhoff[i] = 4096 + c * BK + soff;
    }

    f32x4 acc[4][4];
#pragma unroll
    for (int m = 0; m < 4; ++m)
#pragma unroll
      for (int n = 0; n < 4; ++n) acc[m][n] = (f32x4){0.f, 0.f, 0.f, 0.f};

    stage(0);
    int cur = 0;
#pragma unroll
    for (int t = 0; t < 8; ++t) {
      if (t + 1 < 8) { stage(cur ? 0 : 8192); VMCNT4; }
      else { VMCNT0; }
      SBAR();
      const short* rb = lds + (cur ? 8192 : 0);
      short8 af[4], bh8[4];
#pragma unroll
      for (int i = 0; i < 4; ++i) {
        af[i]  = *(const short8*)(rb + aoff[i]);
        bh8[i] = *(const short8*)(rb + bhoff[i]);
      }
#pragma unroll
      for (int m = 0; m < 4; ++m)
#pragma unroll
        for (int n = 0; n < 4; ++n)
          acc[m][n] = __builtin_amdgcn_mfma_f32_16x16x32_bf16(af[m], bh8[n], acc[m][n], 0, 0, 0);
      SBAR();
      cur ^= 1;
    }

#pragma unroll
    for (int n = 0; n < 4; ++n) {
      int col = bn + wc * 64 + n * 16 + l15;
      float bv = bias[col];
#pragma unroll
      for (int m = 0; m < 4; ++m) {
        int row0 = bm + wr * 64 + m * 16 + (l4 << 2);
#pragma unroll
        for (int r = 0; r < 4; ++r)
          Obf[(size_t)(row0 + r) * 1024 + col] = f2bf_rne(acc[m][n][r] + bv);
      }
    }
  }
}

// ---------------------------------------------------------------------------
// split-K reduce (8 bf16 slices) + bias + relu -> bf16 planes x_enc / x_dec
__global__ __launch_bounds__(256) void sumrelu_kernel(
    const short* __restrict__ part, const float* __restrict__ b0,
    const float* __restrict__ b1, short* __restrict__ xe,
    short* __restrict__ xd)
{
  int i4 = blockIdx.x * 256 + threadIdx.x;
  size_t S = (size_t)N_NODES * 256;
  size_t base = (size_t)i4 * 4;
  int col = (int)(base & 255);
  float4 b0v = *(const float4*)(b0 + col);
  float4 b1v = *(const float4*)(b1 + col);
  float s0[4] = {}, s1[4] = {};
#pragma unroll
  for (int c = 0; c < 4; ++c) {
    short4 p0 = *(const short4*)(part + (size_t)(2 * c) * S + base);
    short4 p1 = *(const short4*)(part + (size_t)(2 * c + 1) * S + base);
    s0[0] += bf2f(p0.x); s0[1] += bf2f(p0.y); s0[2] += bf2f(p0.z); s0[3] += bf2f(p0.w);
    s1[0] += bf2f(p1.x); s1[1] += bf2f(p1.y); s1[2] += bf2f(p1.z); s1[3] += bf2f(p1.w);
  }
  short4 e, d;
  e.x = f2bf_rne(fmaxf(s0[0] + b0v.x, 0.f));
  e.y = f2bf_rne(fmaxf(s0[1] + b0v.y, 0.f));
  e.z = f2bf_rne(fmaxf(s0[2] + b0v.z, 0.f));
  e.w = f2bf_rne(fmaxf(s0[3] + b0v.w, 0.f));
  d.x = f2bf_rne(fmaxf(s1[0] + b1v.x, 0.f));
  d.y = f2bf_rne(fmaxf(s1[1] + b1v.y, 0.f));
  d.z = f2bf_rne(fmaxf(s1[2] + b1v.z, 0.f));
  d.w = f2bf_rne(fmaxf(s1[3] + b1v.w, 0.f));
  *(short4*)(xe + base) = e;
  *(short4*)(xd + base) = d;
}

// ---------------------------------------------------------------------------
// Mega-B: GATv2 (2048 blocks, bucket-CSR) || zsum (512 blocks).
__global__ __launch_bounds__(256) void megaB_kernel(
    const short* __restrict__ xl, const short* __restrict__ xr,
    const float* __restrict__ att, const float* __restrict__ bias,
    const int* __restrict__ csr, const int* __restrict__ cursor,
    short* __restrict__ outp,
    const float* __restrict__ mean_in, const float* __restrict__ lv_in,
    const float* __restrict__ eps, float* __restrict__ z,
    float* __restrict__ csz)
{
  __shared__ float xr_s[HH];
  __shared__ float att_s[HH];
  __shared__ float e_s[8 * CHUNK];
  __shared__ int   src_s[CHUNK];
  __shared__ float m_s[8], s_s[8], f_s[8];

  int tid = threadIdx.x;

  if (blockIdx.x >= 2048) {
    int flat = blockIdx.x - 2048;             // 512 blocks
    int c = ((flat & 3) * 256 + tid) * 2;
    int r0 = (flat >> 2) * 16;
    float sx = 0.f, sy = 0.f;
    for (int r = r0; r < r0 + 16; ++r) {
      size_t off = (size_t)r * 2048 + c;
      float2 m = *(const float2*)(mean_in + off);
      float2 v = *(const float2*)(lv_in + off);
      float2 e = *(const float2*)(eps + off);
      float zx = m.x + expf(0.5f * v.x) * e.x;
      float zy = m.y + expf(0.5f * v.y) * e.y;
      *(float2*)(z + off) = make_float2(zx, zy);
      sx += zx; sy += zy;
    }
    atomicAdd(&csz[c], sx);
    atomicAdd(&csz[c + 1], sy);
    return;
  }

  int n = blockIdx.x;
  {
    short4 x4 = ((const short4*)(xr + (size_t)n * HH))[tid];
    xr_s[tid * 4 + 0] = bf2f(x4.x);
    xr_s[tid * 4 + 1] = bf2f(x4.y);
    xr_s[tid * 4 + 2] = bf2f(x4.z);
    xr_s[tid * 4 + 3] = bf2f(x4.w);
  }
  ((float4*)att_s)[tid] = ((const float4*)att)[tid];
  if (tid < 8) { m_s[tid] = -INFINITY; s_s[tid] = 0.f; }
  __syncthreads();

  int beg = n << 7;
  int cnt_total = min(cursor[n], 128);
  int end = beg + cnt_total;
  int ht = tid >> 5;
  float4 acc = make_float4(0.f, 0.f, 0.f, 0.f);

  for (int c0 = beg; c0 < end; c0 += CHUNK) {
    int cnt = min(CHUNK, end - c0);
    if (tid < cnt) src_s[tid] = csr[c0 + tid];
    __syncthreads();

    int wave = tid >> 6, lane = tid & 63;
    int d0 = lane << 4;
    for (int e = wave; e < cnt; e += 4) {
      const short* xlr = xl + (size_t)src_s[e] * HH + d0;
      short8 a0 = *(const short8*)xlr;
      short8 a1 = *(const short8*)(xlr + 8);
      float sum = 0.f;
#pragma unroll
      for (int j = 0; j < 8; ++j) {
        float t = bf2f(a0[j]) + xr_s[d0 + j];
        t = t > 0.f ? t : 0.2f * t;
        sum += t * att_s[d0 + j];
      }
#pragma unroll
      for (int j = 0; j < 8; ++j) {
        float t = bf2f(a1[j]) + xr_s[d0 + 8 + j];
        t = t > 0.f ? t : 0.2f * t;
        sum += t * att_s[d0 + 8 + j];
      }
      sum += __shfl_xor(sum, 1);
      sum += __shfl_xor(sum, 2);
      sum += __shfl_xor(sum, 4);
      if ((lane & 7) == 0) e_s[(lane >> 3) * CHUNK + e] = sum;
    }
    __syncthreads();

    // wave-parallel online-softmax bookkeeping: 32 threads per head
    {
      int h = tid >> 5, i0 = tid & 31;
      float cm = -INFINITY;
      for (int e = i0; e < cnt; e += 32) cm = fmaxf(cm, e_s[h * CHUNK + e]);
#pragma unroll
      for (int m = 1; m < 32; m <<= 1) cm = fmaxf(cm, __shfl_xor(cm, m));
      float m_old = m_s[h];
      float m_new = fmaxf(m_old, cm);
      float csum = 0.f;
      for (int e = i0; e < cnt; e += 32) {
        float p = expf(e_s[h * CHUNK + e] - m_new);
        e_s[h * CHUNK + e] = p;
        csum += p;
      }
#pragma unroll
      for (int m = 1; m < 32; m <<= 1) csum += __shfl_xor(csum, m);
      if (i0 == 0) {
        float f = expf(m_old - m_new);
        s_s[h] = s_s[h] * f + csum;
        m_s[h] = m_new;
        f_s[h] = f;
      }
    }
    __syncthreads();

    float f = f_s[ht];
    acc.x *= f; acc.y *= f; acc.z *= f; acc.w *= f;
    for (int e = 0; e < cnt; ++e) {
      float p = e_s[ht * CHUNK + e];
      short4 v = *(const short4*)(xl + (size_t)src_s[e] * HH + (tid << 2));
      acc.x += p * bf2f(v.x); acc.y += p * bf2f(v.y);
      acc.z += p * bf2f(v.z); acc.w += p * bf2f(v.w);
    }
    __syncthreads();
  }

  float inv = 1.0f / s_s[ht];
  float4 b4 = *(const float4*)(bias + (tid << 2));
  short4 o4;
  o4.x = f2bf_rne(fmaxf(acc.x * inv + b4.x, 0.f));
  o4.y = f2bf_rne(fmaxf(acc.y * inv + b4.y, 0.f));
  o4.z = f2bf_rne(fmaxf(acc.z * inv + b4.z, 0.f));
  o4.w = f2bf_rne(fmaxf(acc.w * inv + b4.w, 0.f));
  *(short4*)(outp + (size_t)n * HH + (tid << 2)) = o4;
}

// ---------------------------------------------------------------------------
// x_rec = part0 + part1 + bias (f32 out), fused csx. grid (4,128).
// The exact rank-1 lo-plane correction csx[c] += sum_k cs_gat[k]*dfL[c][k]
// is DISTRIBUTED over the 128 by-groups (8 k each).
__global__ __launch_bounds__(256) void xrec_sum_kernel(
    const short* __restrict__ part, const float* __restrict__ bias,
    float* __restrict__ xrec, float* __restrict__ csx,
    const float* __restrict__ cs_gat, const short* __restrict__ dfL)
{
  int c = (blockIdx.x * 256 + threadIdx.x) * 2;
  int r0 = blockIdx.y * 16;
  size_t S = (size_t)N_NODES * 2048;
  float2 b = *(const float2*)(bias + c);
  float sx = 0.f, sy = 0.f;
  for (int r = r0; r < r0 + 16; ++r) {
    size_t off = (size_t)r * 2048 + c;
    short2 p0 = *(const short2*)(part + off);
    short2 p1 = *(const short2*)(part + S + off);
    float vx = bf2f(p0.x) + bf2f(p1.x) + b.x;
    float vy = bf2f(p0.y) + bf2f(p1.y) + b.y;
    *(float2*)(xrec + off) = make_float2(vx, vy);
    sx += vx; sy += vy;
  }
  {
    int k0 = blockIdx.y * 8;
    const short* rw0 = dfL + (size_t)c * 1024 + k0;
    const short* rw1 = dfL + (size_t)(c + 1) * 1024 + k0;
#pragma unroll
    for (int j = 0; j < 8; j += 4) {
      float4 g = *(const float4*)(cs_gat + k0 + j);
      short4 w0 = *(const short4*)(rw0 + j);
      short4 w1 = *(const short4*)(rw1 + j);
      sx += g.x * bf2f(w0.x) + g.y * bf2f(w0.y) + g.z * bf2f(w0.z) + g.w * bf2f(w0.w);
      sy += g.x * bf2f(w1.x) + g.y * bf2f(w1.y) + g.z * bf2f(w1.z) + g.w * bf2f(w1.w);
    }
  }
  atomicAdd(&csx[c], sx);
  atomicAdd(&csx[c + 1], sy);
}

// ---------------------------------------------------------------------------
__global__ __launch_bounds__(256) void final_kernel(
    const float* __restrict__ Ad, const float* __restrict__ Ai,
    const float* __restrict__ gum, const float* __restrict__ csx,
    const float* __restrict__ csz, float* __restrict__ ce_out,
    float* __restrict__ adj_out)
{
  int i = blockIdx.x;
  int tid = threadIdx.x;
  size_t rb = (size_t)i * 2048;

  float vmax = -INFINITY; int vidx = 0;
  for (int j4 = tid; j4 < 512; j4 += 256) {
    float4 ad = *(const float4*)(Ad  + rb + (size_t)j4 * 4);
    float4 ai = *(const float4*)(Ai  + rb + (size_t)j4 * 4);
    float4 g  = *(const float4*)(gum + rb + (size_t)j4 * 4);
    float4 cx = *(const float4*)(csx + (size_t)j4 * 4);
    float4 cz = *(const float4*)(csz + (size_t)j4 * 4);
    float4 ce;
    ce.x = ad.x * cx.x + ai.x * cz.x;
    ce.y = ad.y * cx.y + ai.y * cz.y;
    ce.z = ad.z * cx.z + ai.z * cz.z;
    ce.w = ad.w * cx.w + ai.w * cz.w;
    *(float4*)(ce_out + rb + (size_t)j4 * 4) = ce;
    int j = j4 * 4;
    float l;
    l = (ce.x + g.x) * 2.0f; if (l > vmax) { vmax = l; vidx = j; }
    l = (ce.y + g.y) * 2.0f; if (l > vmax) { vmax = l; vidx = j + 1; }
    l = (ce.z + g.z) * 2.0f; if (l > vmax) { vmax = l; vidx = j + 2; }
    l = (ce.w + g.w) * 2.0f; if (l > vmax) { vmax = l; vidx = j + 3; }
  }
  for (int m = 1; m < 64; m <<= 1) {
    float ov = __shfl_xor(vmax, m);
    int   oi = __shfl_xor(vidx, m);
    if (ov > vmax || (ov == vmax && oi < vidx)) { vmax = ov; vidx = oi; }
  }
  __shared__ float wm[4];
  __shared__ int   wi[4];
  __shared__ int   amax;
  int lane = tid & 63, wave = tid >> 6;
  if (lane == 0) { wm[wave] = vmax; wi[wave] = vidx; }
  __syncthreads();
  if (tid == 0) {
    float bv = wm[0]; int bi = wi[0];
    for (int w = 1; w < 4; ++w)
      if (wm[w] > bv || (wm[w] == bv && wi[w] < bi)) { bv = wm[w]; bi = wi[w]; }
    amax = bi;
  }
  __syncthreads();
  int am = amax;
  for (int j4 = tid; j4 < 512; j4 += 256) {
    int j = j4 * 4;
    float4 o;
    o.x = (j     == am) ? 1.f : 0.f;
    o.y = (j + 1 == am) ? 1.f : 0.f;
    o.z = (j + 2 == am) ? 1.f : 0.f;
    o.w = (j + 3 == am) ? 1.f : 0.f;
    *(float4*)(adj_out + rb + (size_t)j4 * 4) = o;
  }
}

// ---------------------------------------------------------------------------
extern "C" void kernel_launch(void* const* d_in, const int* in_sizes, int n_in,
                              void* d_out, int out_size, void* d_ws, size_t ws_size,
                              hipStream_t stream) {
  (void)in_sizes; (void)n_in; (void)out_size; (void)ws_size;

  const int*   edge_index = (const int*)d_in[4];   // [2, E]
  const float* lagged     = (const float*)d_in[5];
  const float* eps        = (const float*)d_in[6];
  const float* gumbel     = (const float*)d_in[7];
  const float* enc_Wv     = (const float*)d_in[22];
  const float* enc_bv     = (const float*)d_in[23];
  const float* enc_fc_W   = (const float*)d_in[24];
  const float* enc_fc_b   = (const float*)d_in[25];
  const float* dec_Wv     = (const float*)d_in[30];
  const float* dec_bv     = (const float*)d_in[31];
  const float* gat_Wl     = (const float*)d_in[32];
  const float* gat_bl     = (const float*)d_in[33];
  const float* gat_Wr     = (const float*)d_in[34];
  const float* gat_br     = (const float*)d_in[35];
  const float* gat_att    = (const float*)d_in[36];
  const float* gat_bias   = (const float*)d_in[37];
  const float* dec_fc_W   = (const float*)d_in[38];
  const float* dec_fc_b   = (const float*)d_in[39];
  const float* A_dir      = (const float*)d_in[40];
  const float* A_ind      = (const float*)d_in[41];

  float* out      = (float*)d_out;
  float* out_z    = out;
  float* out_mean = out + (size_t)NL;
  float* out_lv   = out + 2 * (size_t)NL;
  float* out_xrec = out + 3 * (size_t)NL;
  float* out_ce   = out + 4 * (size_t)NL;
  float* out_adj  = out + 5 * (size_t)NL;

  char* ws = (char*)d_ws;
  short* lw_bf = (short*)(ws);                                    //  8 MB
  short* WvH0  = (short*)(ws + ((size_t) 8 << 20));
  short* WvH1  = (short*)(ws + ((size_t)10 << 20));
  short* fcH   = (short*)(ws + ((size_t)12 << 20));               //  2 MB
  short* fcL   = (short*)(ws + ((size_t)14 << 20));
  short* WlH   = (short*)(ws + ((size_t)16 << 20));               // .5 MB
  short* WlL   = (short*)(ws + ((size_t)16 << 20) + (512u << 10));
  short* WrH   = (short*)(ws + ((size_t)17 << 20));
  short* WrL   = (short*)(ws + ((size_t)17 << 20) + (512u << 10));
  short* dfH   = (short*)(ws + ((size_t)18 << 20));               //  4 MB
  short* dfL   = (short*)(ws + ((size_t)22 << 20));
  short* xe_bf = (short*)(ws + ((size_t)26 << 20));               //  1 MB
  short* xd_bf = (short*)(ws + ((size_t)27 << 20));
  short* xl    = (short*)(ws + ((size_t)28 << 20));               //  4 MB
  short* xr    = (short*)(ws + ((size_t)32 << 20));               //  4 MB
  short* gt_bf = (short*)(ws + ((size_t)44 << 20));               //  4 MB
  short* part  = (short*)(ws + ((size_t)48 << 20));               // 16 MB
  int*   cursor = (int*) (ws + ((size_t)64 << 20));               //  8 KB
  int*   csr    = (int*) (ws + ((size_t)64 << 20) + (64u << 10)); //  1 MB
  float* csx    = (float*)(ws + ((size_t)66 << 20));
  float* csz    = (float*)(ws + ((size_t)66 << 20) + (16u << 10));
  float* cs_gat = (float*)(ws + ((size_t)66 << 20) + (32u << 10));

  const int* e_src = edge_index;
  const int* e_dst = edge_index + NE;

  // Mega-A: lw || encWv/decWv H-plane split || init (cursor/csx/csz/cs_gat)
  {
    WCfg2 c2;
    c2.c[0] = { enc_Wv, WvH0, nullptr, 2048, 256, 512 };
    c2.c[1] = { dec_Wv, WvH1, nullptr, 2048, 256, 512 };
    megaA_kernel<<<3080, 256, 0, stream>>>(lagged, lw_bf, c2,
                                           cursor, csx, csz, cs_gat);
  }

  // Mega-C: encV/decV GEMM (split-K x4) || weight splits || bucket-CSR fill
  {
    WCfg4 c4;
    c4.c[0] = { enc_fc_W, fcH, fcL, 256,  4096, 1024 };
    c4.c[1] = { gat_Wl,   WlH, WlL, 256,  1024, 256  };
    c4.c[2] = { gat_Wr,   WrH, WrL, 256,  1024, 256  };
    c4.c[3] = { dec_fc_W, dfH, dfL, 1024, 2048, 2048 };
    megaC_kernel<<<4104, 256, 0, stream>>>(
        lw_bf, WvH0, WvH1, part, c4, e_src, e_dst, cursor, csr);
  }

  // split-K reduce (8 slices) -> x_enc/x_dec (bf16)
  sumrelu_kernel<<<512, 256, 0, stream>>>(part, enc_bv, dec_bv, xe_bf, xd_bf);

  // merged: q_params GEMM (mean/lv, hi/lo) + xl/xr GEMM (single-plane)
  gemm_dual<<<768, 256, 0, stream>>>(
      xe_bf, xd_bf, fcH, fcL, WlH, WrH,
      enc_fc_b, gat_bl, gat_br, out_mean, out_lv, xl, xr);

  // Mega-B: GATv2 || zsum (z + csz)
  megaB_kernel<<<2560, 256, 0, stream>>>(
      xl, xr, gat_att, gat_bias, csr, cursor, gt_bf,
      out_mean, out_lv, eps, out_z, csz);

  // x_rec GEMM: hi-plane only, split-K x2; bn==0 blocks also colsum gt_bf
  gemm_xrec<<<dim3(16, 16, 2), 256, 0, stream>>>(gt_bf, dfH, part, cs_gat);
  xrec_sum_kernel<<<dim3(4, 128), 256, 0, stream>>>(
      part, dec_fc_b, out_xrec, csx, cs_gat, dfL);

  // causal effect + hard gumbel one-hot
  final_kernel<<<N_NODES, 256, 0, stream>>>(A_dir, A_ind, gumbel, csx, csz,
                                            out_ce, out_adj);
}